// Round 1
// baseline (697.136 us; speedup 1.0000x reference)
//
#include <hip/hip_runtime.h>
#include <math.h>

#define BN 4
#define NN 2048
#define DD 256
#define EPSF 1e-5f

// ---- output layout (float offsets) ----
constexpr size_t OFF_EST = 0;                                  // (B,2,N,D)
constexpr size_t OFF_OUT = (size_t)BN * 2 * NN * DD;           // (B,2,N,D)
constexpr size_t OFF_QIJ = OFF_OUT + (size_t)BN * 2 * NN * DD; // (B,2,N,N)
constexpr size_t OFF_VV  = OFF_QIJ + (size_t)BN * 2 * NN * NN; // (1,2,N,D)
constexpr size_t OFF_UV  = OFF_VV + (size_t)2 * NN * DD;       // (B,2,N,D)
constexpr size_t OFF_LH  = OFF_UV + (size_t)BN * 2 * NN * DD;  // (2,D,1)

// ---- scratch carved out of the Q_ij imaginary-channel regions (zeroed last) ----
constexpr size_t SCR_QR = OFF_QIJ + (size_t)NN * NN;           // b0 imag region
constexpr size_t SCR_KR = SCR_QR + (size_t)BN * NN * DD;
constexpr size_t SCR_VR = OFF_QIJ + (size_t)3 * NN * NN;       // b1 imag region
constexpr size_t SCR_QN = OFF_QIJ + (size_t)5 * NN * NN;       // b2 imag region
constexpr size_t SCR_KN = SCR_QN + (size_t)BN * NN;
constexpr size_t SCR_L  = SCR_KN + (size_t)BN * NN;
constexpr size_t SCR_SC = SCR_L + (size_t)BN * NN;             // [tau2, s, ga_bar, om_bar]

// =====================================================================
// prep: scalars + zero the row-sum accumulator
// =====================================================================
__global__ void k_prep(const float* __restrict__ tau, const float* __restrict__ delta,
                       const float* __restrict__ lamOm, const float* __restrict__ lamGa,
                       const float* __restrict__ lamC, float* __restrict__ dout) {
    __shared__ float red[8];
    const int t = threadIdx.x;
    float c2 = lamC[t] * lamC[t];
    float ga = c2 * (lamGa[t] * lamGa[t] + EPSF);
    float om = c2 * (lamOm[t] * lamOm[t] + EPSF);
    for (int o = 32; o > 0; o >>= 1) {
        ga += __shfl_down(ga, o, 64);
        om += __shfl_down(om, o, 64);
    }
    if ((t & 63) == 0) { red[t >> 6] = ga; red[4 + (t >> 6)] = om; }
    __syncthreads();
    if (t == 0) {
        float gs = red[0] + red[1] + red[2] + red[3];
        float os = red[4] + red[5] + red[6] + red[7];
        float* scal = dout + SCR_SC;
        scal[0] = tau[0] * tau[0];
        scal[1] = 1.f / (1.f + __expf(-delta[0]));
        scal[2] = gs / 256.f;
        scal[3] = os / 256.f;
    }
    float* L = dout + SCR_L;
    for (int i = t; i < BN * NN; i += 256) L[i] = 0.f;
}

// =====================================================================
// complex-linear tiled GEMM helper: 64x64 tile, K=512, fp32
// mode 0: real out (Zr@Wr^T - Zi@Wi^T + b[0]); mode 1: imag out (Zr@Wi^T + Zi@Wr^T + b[1])
// =====================================================================
__device__ __forceinline__ void clinear_tile(
    const float* __restrict__ Z, const float* __restrict__ W,
    const float* __restrict__ bias, int mode, int b, int n0, int d0,
    float* __restrict__ O, int o_interleaved,
    float* __restrict__ O2, int o2_mode,   // 0 none, 1 copy, 2 scale by (1-s)
    const float* __restrict__ scal,
    float* __restrict__ As, float* __restrict__ Ws) {
    const int t  = threadIdx.x;
    const int tx = t & 15, ty = t >> 4;
    const int lrow = t >> 3;         // 0..31
    const int lkq  = (t & 7) << 2;   // 0..28

    float acc[4][4] = {{0.f,0.f,0.f,0.f},{0.f,0.f,0.f,0.f},{0.f,0.f,0.f,0.f},{0.f,0.f,0.f,0.f}};

    for (int kt = 0; kt < 16; ++kt) {
        const int c   = kt >> 3;
        const int kk0 = (kt & 7) * 32;
        const float* Zb = Z + ((size_t)(b * 2 + c) * NN + n0) * DD + kk0;
        float4 a0 = *(const float4*)(Zb + (size_t)lrow * DD + lkq);
        float4 a1 = *(const float4*)(Zb + (size_t)(lrow + 32) * DD + lkq);
        int wc; float sgn;
        if (mode == 0) { wc = c; sgn = c ? -1.f : 1.f; }
        else           { wc = 1 - c; sgn = 1.f; }
        const float* Wb = W + ((size_t)wc * DD + d0) * DD + kk0;
        float4 w0 = *(const float4*)(Wb + (size_t)lrow * DD + lkq);
        float4 w1 = *(const float4*)(Wb + (size_t)(lrow + 32) * DD + lkq);
        __syncthreads();
        As[(lkq + 0) * 68 + lrow] = a0.x; As[(lkq + 1) * 68 + lrow] = a0.y;
        As[(lkq + 2) * 68 + lrow] = a0.z; As[(lkq + 3) * 68 + lrow] = a0.w;
        As[(lkq + 0) * 68 + lrow + 32] = a1.x; As[(lkq + 1) * 68 + lrow + 32] = a1.y;
        As[(lkq + 2) * 68 + lrow + 32] = a1.z; As[(lkq + 3) * 68 + lrow + 32] = a1.w;
        Ws[(lkq + 0) * 68 + lrow] = sgn * w0.x; Ws[(lkq + 1) * 68 + lrow] = sgn * w0.y;
        Ws[(lkq + 2) * 68 + lrow] = sgn * w0.z; Ws[(lkq + 3) * 68 + lrow] = sgn * w0.w;
        Ws[(lkq + 0) * 68 + lrow + 32] = sgn * w1.x; Ws[(lkq + 1) * 68 + lrow + 32] = sgn * w1.y;
        Ws[(lkq + 2) * 68 + lrow + 32] = sgn * w1.z; Ws[(lkq + 3) * 68 + lrow + 32] = sgn * w1.w;
        __syncthreads();
#pragma unroll
        for (int kk = 0; kk < 32; ++kk) {
            const float4 a = *(const float4*)&As[kk * 68 + (ty << 2)];
            const float4 w = *(const float4*)&Ws[kk * 68 + (tx << 2)];
            acc[0][0] = fmaf(a.x, w.x, acc[0][0]); acc[0][1] = fmaf(a.x, w.y, acc[0][1]);
            acc[0][2] = fmaf(a.x, w.z, acc[0][2]); acc[0][3] = fmaf(a.x, w.w, acc[0][3]);
            acc[1][0] = fmaf(a.y, w.x, acc[1][0]); acc[1][1] = fmaf(a.y, w.y, acc[1][1]);
            acc[1][2] = fmaf(a.y, w.z, acc[1][2]); acc[1][3] = fmaf(a.y, w.w, acc[1][3]);
            acc[2][0] = fmaf(a.z, w.x, acc[2][0]); acc[2][1] = fmaf(a.z, w.y, acc[2][1]);
            acc[2][2] = fmaf(a.z, w.z, acc[2][2]); acc[2][3] = fmaf(a.z, w.w, acc[2][3]);
            acc[3][0] = fmaf(a.w, w.x, acc[3][0]); acc[3][1] = fmaf(a.w, w.y, acc[3][1]);
            acc[3][2] = fmaf(a.w, w.z, acc[3][2]); acc[3][3] = fmaf(a.w, w.w, acc[3][3]);
        }
    }
    const int boff = mode ? DD : 0;
    const float4 bv = *(const float4*)&bias[boff + d0 + (tx << 2)];
    float s1 = 1.f;
    if (o2_mode == 2) s1 = 1.f - scal[1];
#pragma unroll
    for (int i = 0; i < 4; ++i) {
        const int n = n0 + (ty << 2) + i;
        float4 o;
        o.x = acc[i][0] + bv.x; o.y = acc[i][1] + bv.y;
        o.z = acc[i][2] + bv.z; o.w = acc[i][3] + bv.w;
        if (O) {
            size_t oi = o_interleaved ? (((size_t)b * 2 * NN + n) * DD + d0 + (tx << 2))
                                      : (((size_t)b * NN + n) * DD + d0 + (tx << 2));
            *(float4*)&O[oi] = o;
        }
        if (o2_mode) {
            size_t oi2 = ((size_t)b * 2 * NN + n) * DD + d0 + (tx << 2);
            float4 e; e.x = s1 * o.x; e.y = s1 * o.y; e.z = s1 * o.z; e.w = s1 * o.w;
            *(float4*)&O2[oi2] = e;
        }
    }
}

// z: 0=Qr, 1=Kr, 2=Vr (+U_v ch0), 3=Vi -> est ch1 = (1-s)*Vi
__global__ __launch_bounds__(256) void k_qkv(
    const float* __restrict__ Zq, const float* __restrict__ Zk, const float* __restrict__ Zv,
    const float* __restrict__ Wq, const float* __restrict__ bq,
    const float* __restrict__ Wk, const float* __restrict__ bk,
    const float* __restrict__ Wv, const float* __restrict__ bv,
    float* __restrict__ dout) {
    __shared__ float As[32 * 68];
    __shared__ float Ws[32 * 68];
    const int z = blockIdx.z;
    const int d0 = blockIdx.x * 64;
    const int r0 = blockIdx.y * 64;
    const int b = r0 / NN, n0 = r0 % NN;
    const float* scal = dout + SCR_SC;
    if (z == 0)
        clinear_tile(Zq, Wq, bq, 0, b, n0, d0, dout + SCR_QR, 0, nullptr, 0, scal, As, Ws);
    else if (z == 1)
        clinear_tile(Zk, Wk, bk, 0, b, n0, d0, dout + SCR_KR, 0, nullptr, 0, scal, As, Ws);
    else if (z == 2)
        clinear_tile(Zv, Wv, bv, 0, b, n0, d0, dout + SCR_VR, 0, dout + OFF_UV, 1, scal, As, Ws);
    else
        clinear_tile(Zv, Wv, bv, 1, b, n0, d0, nullptr, 0,
                     dout + OFF_EST + (size_t)NN * DD, 2, scal, As, Ws);
}

__global__ __launch_bounds__(256) void k_outproj(
    const float* __restrict__ Wp, const float* __restrict__ bp, float* __restrict__ dout) {
    __shared__ float As[32 * 68];
    __shared__ float Ws[32 * 68];
    const int z = blockIdx.z;
    const int d0 = blockIdx.x * 64;
    const int r0 = blockIdx.y * 64;
    const int b = r0 / NN, n0 = r0 % NN;
    const float* est = dout + OFF_EST;
    float* O = dout + OFF_OUT + (size_t)z * NN * DD;  // channel pre-offset
    clinear_tile(est, Wp, bp, z, b, n0, d0, O, 1, nullptr, 0, dout + SCR_SC, As, Ws);
}

// =====================================================================
// row squared-norms of Qr / Kr
// =====================================================================
__global__ __launch_bounds__(256) void k_norms(float* __restrict__ dout) {
    const int r = blockIdx.x;
    const float* src = dout + (blockIdx.y ? SCR_KR : SCR_QR);
    float v = src[(size_t)r * DD + threadIdx.x];
    float p = v * v;
    for (int o = 32; o > 0; o >>= 1) p += __shfl_down(p, o, 64);
    __shared__ float red[4];
    if ((threadIdx.x & 63) == 0) red[threadIdx.x >> 6] = p;
    __syncthreads();
    if (threadIdx.x == 0)
        dout[(blockIdx.y ? SCR_KN : SCR_QN) + r] = red[0] + red[1] + red[2] + red[3];
}

// =====================================================================
// causal score tiles: unnormalized w = x^{-tau^2}, x = ga + om|ti-tj| + ||Qi-Kj||^2
// writes w into Q_ij ch0 (zeros above diag within tile), row sums into L
// =====================================================================
__global__ __launch_bounds__(256) void k_scores(const float* __restrict__ tmeas,
                                                float* __restrict__ dout) {
    const int b = blockIdx.y;
    const int x = blockIdx.x;
    int ti = (int)((sqrtf(8.f * x + 1.f) - 1.f) * 0.5f);
    while ((ti + 1) * (ti + 2) / 2 <= x) ++ti;
    while (ti * (ti + 1) / 2 > x) --ti;
    const int tj = x - ti * (ti + 1) / 2;
    const int i0 = ti * 64, j0 = tj * 64;
    const float* QR = dout + SCR_QR;
    const float* KR = dout + SCR_KR;
    const float* scal = dout + SCR_SC;

    __shared__ float Qs[32 * 68];
    __shared__ float Ks[32 * 68];
    const int t = threadIdx.x, tx = t & 15, ty = t >> 4;
    const int lrow = t >> 3, lkq = (t & 7) << 2;
    float acc[4][4] = {{0.f,0.f,0.f,0.f},{0.f,0.f,0.f,0.f},{0.f,0.f,0.f,0.f},{0.f,0.f,0.f,0.f}};

    for (int kt = 0; kt < 8; ++kt) {
        const int kk0 = kt * 32;
        const float* Qb = QR + ((size_t)b * NN + i0) * DD + kk0;
        const float* Kb = KR + ((size_t)b * NN + j0) * DD + kk0;
        float4 q0 = *(const float4*)(Qb + (size_t)lrow * DD + lkq);
        float4 q1 = *(const float4*)(Qb + (size_t)(lrow + 32) * DD + lkq);
        float4 k0 = *(const float4*)(Kb + (size_t)lrow * DD + lkq);
        float4 k1 = *(const float4*)(Kb + (size_t)(lrow + 32) * DD + lkq);
        __syncthreads();
        Qs[(lkq + 0) * 68 + lrow] = q0.x; Qs[(lkq + 1) * 68 + lrow] = q0.y;
        Qs[(lkq + 2) * 68 + lrow] = q0.z; Qs[(lkq + 3) * 68 + lrow] = q0.w;
        Qs[(lkq + 0) * 68 + lrow + 32] = q1.x; Qs[(lkq + 1) * 68 + lrow + 32] = q1.y;
        Qs[(lkq + 2) * 68 + lrow + 32] = q1.z; Qs[(lkq + 3) * 68 + lrow + 32] = q1.w;
        Ks[(lkq + 0) * 68 + lrow] = k0.x; Ks[(lkq + 1) * 68 + lrow] = k0.y;
        Ks[(lkq + 2) * 68 + lrow] = k0.z; Ks[(lkq + 3) * 68 + lrow] = k0.w;
        Ks[(lkq + 0) * 68 + lrow + 32] = k1.x; Ks[(lkq + 1) * 68 + lrow + 32] = k1.y;
        Ks[(lkq + 2) * 68 + lrow + 32] = k1.z; Ks[(lkq + 3) * 68 + lrow + 32] = k1.w;
        __syncthreads();
#pragma unroll
        for (int kk = 0; kk < 32; ++kk) {
            const float4 a = *(const float4*)&Qs[kk * 68 + (ty << 2)];
            const float4 w = *(const float4*)&Ks[kk * 68 + (tx << 2)];
            acc[0][0] = fmaf(a.x, w.x, acc[0][0]); acc[0][1] = fmaf(a.x, w.y, acc[0][1]);
            acc[0][2] = fmaf(a.x, w.z, acc[0][2]); acc[0][3] = fmaf(a.x, w.w, acc[0][3]);
            acc[1][0] = fmaf(a.y, w.x, acc[1][0]); acc[1][1] = fmaf(a.y, w.y, acc[1][1]);
            acc[1][2] = fmaf(a.y, w.z, acc[1][2]); acc[1][3] = fmaf(a.y, w.w, acc[1][3]);
            acc[2][0] = fmaf(a.z, w.x, acc[2][0]); acc[2][1] = fmaf(a.z, w.y, acc[2][1]);
            acc[2][2] = fmaf(a.z, w.z, acc[2][2]); acc[2][3] = fmaf(a.z, w.w, acc[2][3]);
            acc[3][0] = fmaf(a.w, w.x, acc[3][0]); acc[3][1] = fmaf(a.w, w.y, acc[3][1]);
            acc[3][2] = fmaf(a.w, w.z, acc[3][2]); acc[3][3] = fmaf(a.w, w.w, acc[3][3]);
        }
    }

    const float tau2 = scal[0], ga = scal[2], om = scal[3];
    float qn[4], tq[4];
#pragma unroll
    for (int i = 0; i < 4; ++i) {
        const int irow = i0 + (ty << 2) + i;
        qn[i] = dout[SCR_QN + b * NN + irow];
        tq[i] = tmeas[irow];
    }
    float kn[4], tj_t[4];
#pragma unroll
    for (int j = 0; j < 4; ++j) {
        const int jcol = j0 + (tx << 2) + j;
        kn[j] = dout[SCR_KN + b * NN + jcol];
        tj_t[j] = tmeas[jcol];
    }
    float* Qij = dout + OFF_QIJ + (size_t)b * 2 * NN * NN;
#pragma unroll
    for (int i = 0; i < 4; ++i) {
        const int irow = i0 + (ty << 2) + i;
        float w4[4];
#pragma unroll
        for (int j = 0; j < 4; ++j) {
            const int jcol = j0 + (tx << 2) + j;
            float xx = ga + om * fabsf(tq[i] - tj_t[j]) + qn[i] + kn[j] - 2.f * acc[i][j];
            xx = fmaxf(xx, 1e-30f);
            float w;
            if (tau2 == 1.f) w = 1.f / xx;
            else             w = __expf(-tau2 * __logf(xx));
            w4[j] = (jcol <= irow) ? w : 0.f;
        }
        float4 wv; wv.x = w4[0]; wv.y = w4[1]; wv.z = w4[2]; wv.w = w4[3];
        *(float4*)&Qij[(size_t)irow * NN + j0 + (tx << 2)] = wv;
        float rs = w4[0] + w4[1] + w4[2] + w4[3];
        rs += __shfl_down(rs, 8, 16); rs += __shfl_down(rs, 4, 16);
        rs += __shfl_down(rs, 2, 16); rs += __shfl_down(rs, 1, 16);
        if (tx == 0) atomicAdd(&dout[SCR_L + b * NN + irow], rs);
    }
}

// =====================================================================
// est_inner = (w @ V_r)/l ; est ch0 = (1-s)*Vr + s*est_inner
// =====================================================================
__global__ __launch_bounds__(256) void k_estinner(float* __restrict__ dout) {
    const int b = blockIdx.z, ti = blockIdx.y;
    const int d0 = blockIdx.x * 64, i0 = ti * 64;
    const int nkt = (ti + 1) * 2;  // K = (ti+1)*64, Kt=32
    const float* Qij = dout + OFF_QIJ + (size_t)b * 2 * NN * NN;
    const float* VR = dout + SCR_VR;
    __shared__ float As[32 * 68];
    __shared__ float Bs[32 * 64];
    const int t = threadIdx.x, tx = t & 15, ty = t >> 4;
    const int lrow = t >> 3, lkq = (t & 7) << 2;
    const int brow = t >> 4, bdq = (t & 15) << 2;
    float acc[4][4] = {{0.f,0.f,0.f,0.f},{0.f,0.f,0.f,0.f},{0.f,0.f,0.f,0.f},{0.f,0.f,0.f,0.f}};

    for (int kt = 0; kt < nkt; ++kt) {
        const int j0 = kt * 32;
        const float* Ab = Qij + (size_t)i0 * NN + j0;
        float4 a0 = *(const float4*)(Ab + (size_t)lrow * NN + lkq);
        float4 a1 = *(const float4*)(Ab + (size_t)(lrow + 32) * NN + lkq);
        const float* Bb = VR + ((size_t)b * NN + j0) * DD + d0;
        float4 b0 = *(const float4*)(Bb + (size_t)brow * DD + bdq);
        float4 b1 = *(const float4*)(Bb + (size_t)(brow + 16) * DD + bdq);
        __syncthreads();
        As[(lkq + 0) * 68 + lrow] = a0.x; As[(lkq + 1) * 68 + lrow] = a0.y;
        As[(lkq + 2) * 68 + lrow] = a0.z; As[(lkq + 3) * 68 + lrow] = a0.w;
        As[(lkq + 0) * 68 + lrow + 32] = a1.x; As[(lkq + 1) * 68 + lrow + 32] = a1.y;
        As[(lkq + 2) * 68 + lrow + 32] = a1.z; As[(lkq + 3) * 68 + lrow + 32] = a1.w;
        *(float4*)&Bs[brow * 64 + bdq] = b0;
        *(float4*)&Bs[(brow + 16) * 64 + bdq] = b1;
        __syncthreads();
#pragma unroll
        for (int kk = 0; kk < 32; ++kk) {
            const float4 a = *(const float4*)&As[kk * 68 + (ty << 2)];
            const float4 w = *(const float4*)&Bs[kk * 64 + (tx << 2)];
            acc[0][0] = fmaf(a.x, w.x, acc[0][0]); acc[0][1] = fmaf(a.x, w.y, acc[0][1]);
            acc[0][2] = fmaf(a.x, w.z, acc[0][2]); acc[0][3] = fmaf(a.x, w.w, acc[0][3]);
            acc[1][0] = fmaf(a.y, w.x, acc[1][0]); acc[1][1] = fmaf(a.y, w.y, acc[1][1]);
            acc[1][2] = fmaf(a.y, w.z, acc[1][2]); acc[1][3] = fmaf(a.y, w.w, acc[1][3]);
            acc[2][0] = fmaf(a.z, w.x, acc[2][0]); acc[2][1] = fmaf(a.z, w.y, acc[2][1]);
            acc[2][2] = fmaf(a.z, w.z, acc[2][2]); acc[2][3] = fmaf(a.z, w.w, acc[2][3]);
            acc[3][0] = fmaf(a.w, w.x, acc[3][0]); acc[3][1] = fmaf(a.w, w.y, acc[3][1]);
            acc[3][2] = fmaf(a.w, w.z, acc[3][2]); acc[3][3] = fmaf(a.w, w.w, acc[3][3]);
        }
    }
    const float s = dout[SCR_SC + 1];
#pragma unroll
    for (int i = 0; i < 4; ++i) {
        const int irow = i0 + (ty << 2) + i;
        const float linv = 1.f / dout[SCR_L + b * NN + irow];
        const float4 vr = *(const float4*)&VR[((size_t)b * NN + irow) * DD + d0 + (tx << 2)];
        float4 o;
        o.x = (1.f - s) * vr.x + s * acc[i][0] * linv;
        o.y = (1.f - s) * vr.y + s * acc[i][1] * linv;
        o.z = (1.f - s) * vr.z + s * acc[i][2] * linv;
        o.w = (1.f - s) * vr.w + s * acc[i][3] * linv;
        *(float4*)&dout[OFF_EST + ((size_t)b * 2 * NN + irow) * DD + d0 + (tx << 2)] = o;
    }
}

// normalize Q_ij rows by 1/l (causal region only; zeros stay zero)
__global__ void k_norm_qij(float* __restrict__ dout) {
    const int b = blockIdx.z, i = blockIdx.y;
    const int j0 = blockIdx.x * 1024 + threadIdx.x * 4;
    if (j0 > i) return;
    const float linv = 1.f / dout[SCR_L + b * NN + i];
    float* p = dout + OFF_QIJ + (size_t)b * 2 * NN * NN + (size_t)i * NN + j0;
    float4 v = *(float4*)p;
    v.x *= linv; v.y *= linv; v.z *= linv; v.w *= linv;
    *(float4*)p = v;
}

// strictly-upper tiles of Q_ij ch0 -> 0
__global__ void k_fill_upper(float* __restrict__ dout) {
    const int b = blockIdx.y, i = blockIdx.x;
    const int jstart = ((i >> 6) + 1) << 6;
    float* row = dout + OFF_QIJ + (size_t)b * 2 * NN * NN + (size_t)i * NN;
    const float4 z = {0.f, 0.f, 0.f, 0.f};
    for (int j = jstart + threadIdx.x * 4; j < NN; j += 256 * 4)
        *(float4*)&row[j] = z;
}

__global__ void k_zero(float* __restrict__ p, long n) {
    const float4 z = {0.f, 0.f, 0.f, 0.f};
    for (long i = ((long)blockIdx.x * 256 + threadIdx.x) * 4; i < n; i += (long)gridDim.x * 1024)
        *(float4*)&p[i] = z;
}

__global__ void k_ones(float* __restrict__ p, long n) {
    const float4 z = {1.f, 1.f, 1.f, 1.f};
    for (long i = ((long)blockIdx.x * 256 + threadIdx.x) * 4; i < n; i += (long)gridDim.x * 1024)
        *(float4*)&p[i] = z;
}

extern "C" void kernel_launch(void* const* d_in, const int* in_sizes, int n_in,
                              void* d_out, int out_size, void* d_ws, size_t ws_size,
                              hipStream_t stream) {
    const float* Zq = (const float*)d_in[0];
    const float* Zk = (const float*)d_in[1];
    const float* Zv = (const float*)d_in[2];
    const float* tm = (const float*)d_in[3];
    const float* Wq = (const float*)d_in[4];
    const float* bq = (const float*)d_in[5];
    const float* Wk = (const float*)d_in[6];
    const float* bk = (const float*)d_in[7];
    const float* Wv = (const float*)d_in[8];
    const float* bv = (const float*)d_in[9];
    const float* Wp = (const float*)d_in[10];
    const float* bp = (const float*)d_in[11];
    const float* lamOm = (const float*)d_in[13];
    const float* lamGa = (const float*)d_in[14];
    const float* tau = (const float*)d_in[15];
    const float* delta = (const float*)d_in[16];
    const float* lamC = (const float*)d_in[17];
    float* out = (float*)d_out;

    k_prep<<<dim3(1), dim3(256), 0, stream>>>(tau, delta, lamOm, lamGa, lamC, out);
    k_qkv<<<dim3(4, 128, 4), dim3(256), 0, stream>>>(Zq, Zk, Zv, Wq, bq, Wk, bk, Wv, bv, out);
    k_norms<<<dim3(8192, 2), dim3(256), 0, stream>>>(out);
    k_scores<<<dim3(528, 4), dim3(256), 0, stream>>>(tm, out);
    k_estinner<<<dim3(4, 32, 4), dim3(256), 0, stream>>>(out);
    k_norm_qij<<<dim3(2, 2048, 4), dim3(256), 0, stream>>>(out);
    k_outproj<<<dim3(4, 128, 2), dim3(256), 0, stream>>>(Wp, bp, out);
    k_fill_upper<<<dim3(2048, 4), dim3(256), 0, stream>>>(out);
    // scratch regions (Q_ij imaginary channels) are dead now -> zero them
    for (int b = 0; b < BN; ++b)
        k_zero<<<dim3(4096), dim3(256), 0, stream>>>(
            out + OFF_QIJ + (size_t)(2 * b + 1) * NN * NN, (long)NN * NN);
    k_ones<<<dim3(512), dim3(256), 0, stream>>>(out + OFF_VV, (long)NN * DD);
    k_zero<<<dim3(512), dim3(256), 0, stream>>>(out + OFF_VV + (size_t)NN * DD, (long)NN * DD);
    for (int b = 0; b < BN; ++b)
        k_zero<<<dim3(512), dim3(256), 0, stream>>>(
            out + OFF_UV + (size_t)(2 * b + 1) * NN * DD, (long)NN * DD);
    k_zero<<<dim3(1), dim3(256), 0, stream>>>(out + OFF_LH, 512);
}

// Round 2
// 413.683 us; speedup vs baseline: 1.6852x; 1.6852x over previous
//
#include <hip/hip_runtime.h>
#include <math.h>

#define BN 4
#define NN 2048
#define DD 256
#define EPSF 1e-5f

typedef __attribute__((ext_vector_type(8))) short bf16x8;
typedef __attribute__((ext_vector_type(4))) float f32x4;

// ---- output layout (float offsets) ----
constexpr size_t OFF_EST = 0;                                  // (B,2,N,D)
constexpr size_t OFF_OUT = (size_t)BN * 2 * NN * DD;           // (B,2,N,D)
constexpr size_t OFF_QIJ = OFF_OUT + (size_t)BN * 2 * NN * DD; // (B,2,N,N)
constexpr size_t OFF_VV  = OFF_QIJ + (size_t)BN * 2 * NN * NN; // (1,2,N,D)
constexpr size_t OFF_UV  = OFF_VV + (size_t)2 * NN * DD;       // (B,2,N,D)
constexpr size_t OFF_LH  = OFF_UV + (size_t)BN * 2 * NN * DD;  // (2,D,1)

// ---- scratch in Q_ij imaginary-channel regions (zeroed last) ----
constexpr size_t SCR_Q16 = OFF_QIJ + (size_t)NN * NN;            // bf16 [b][n][d]
constexpr size_t SCR_K16 = SCR_Q16 + (size_t)BN * NN * DD / 2;   // bf16 [b][n][d]
constexpr size_t SCR_VT16= SCR_K16 + (size_t)BN * NN * DD / 2;   // bf16 [b][d][n] (V^T)
constexpr size_t SCR_VRF = OFF_QIJ + (size_t)3 * NN * NN;        // fp32 [b][n][d]
constexpr size_t SCR_QN  = SCR_VRF + (size_t)BN * NN * DD;
constexpr size_t SCR_KN  = SCR_QN + (size_t)BN * NN;
constexpr size_t SCR_L   = SCR_KN + (size_t)BN * NN;
constexpr size_t SCR_SC  = SCR_L + (size_t)BN * NN;              // [tau2, s, ga_bar, om_bar]

__device__ __forceinline__ short f2bf(float x) {
    union { float f; unsigned u; } v; v.f = x;
    unsigned r = v.u + 0x7fff + ((v.u >> 16) & 1);
    return (short)(r >> 16);
}
__device__ __forceinline__ float bf2f(unsigned short h) {
    union { unsigned u; float f; } v; v.u = ((unsigned)h) << 16;
    return v.f;
}

// =====================================================================
// prep: scalars + zero row-sum accumulator
// =====================================================================
__global__ void k_prep(const float* __restrict__ tau, const float* __restrict__ delta,
                       const float* __restrict__ lamOm, const float* __restrict__ lamGa,
                       const float* __restrict__ lamC, float* __restrict__ dout) {
    __shared__ float red[8];
    const int t = threadIdx.x;
    float c2 = lamC[t] * lamC[t];
    float ga = c2 * (lamGa[t] * lamGa[t] + EPSF);
    float om = c2 * (lamOm[t] * lamOm[t] + EPSF);
    for (int o = 32; o > 0; o >>= 1) {
        ga += __shfl_down(ga, o, 64);
        om += __shfl_down(om, o, 64);
    }
    if ((t & 63) == 0) { red[t >> 6] = ga; red[4 + (t >> 6)] = om; }
    __syncthreads();
    if (t == 0) {
        float gs = red[0] + red[1] + red[2] + red[3];
        float os = red[4] + red[5] + red[6] + red[7];
        float* scal = dout + SCR_SC;
        scal[0] = tau[0] * tau[0];
        scal[1] = 1.f / (1.f + __expf(-delta[0]));
        scal[2] = gs / 256.f;
        scal[3] = os / 256.f;
    }
    float* L = dout + SCR_L;
    for (int i = t; i < BN * NN; i += 256) L[i] = 0.f;
}

// =====================================================================
// QKV projection, MFMA bf16: 128x128 macro-tile, 4 waves of 64x64
// z: 0=Qr->Q16, 1=Kr->K16, 2=Vr->VRF+UVch0, 3=Vi->est ch1 = (1-s)*Vi
// =====================================================================
__global__ __launch_bounds__(256) void k_qkv(
    const float* __restrict__ Zq, const float* __restrict__ Zk, const float* __restrict__ Zv,
    const float* __restrict__ Wq, const float* __restrict__ bq,
    const float* __restrict__ Wk, const float* __restrict__ bk,
    const float* __restrict__ Wv, const float* __restrict__ bv,
    float* __restrict__ dout)
{
    __shared__ short Al[128 * 40];
    __shared__ short Bl[128 * 40];
    const int z = blockIdx.z;
    const int d0 = blockIdx.x * 128;
    const int b = blockIdx.y >> 4;
    const int n0 = (blockIdx.y & 15) * 128;
    const float* Z; const float* W; const float* bias; int mode;
    if (z == 0)      { Z = Zq; W = Wq; bias = bq; mode = 0; }
    else if (z == 1) { Z = Zk; W = Wk; bias = bk; mode = 0; }
    else if (z == 2) { Z = Zv; W = Wv; bias = bv; mode = 0; }
    else             { Z = Zv; W = Wv; bias = bv; mode = 1; }

    const int t = threadIdx.x, wave = t >> 6, lane = t & 63, quad = lane >> 4, lm = lane & 15;
    const int wm = (wave >> 1) * 64, wn = (wave & 1) * 64;
    const int srow = t >> 1, sch = (t & 1) * 16;

    f32x4 acc[4][4];
#pragma unroll
    for (int i = 0; i < 4; ++i)
#pragma unroll
        for (int j = 0; j < 4; ++j) acc[i][j] = (f32x4){0.f, 0.f, 0.f, 0.f};

    for (int kt = 0; kt < 16; ++kt) {
        const int c = kt >> 3, kk0 = (kt & 7) * 32;
        const float* Za = Z + ((size_t)((b * 2 + c) * NN + n0 + srow)) * DD + kk0 + sch;
        float4 a0 = *(const float4*)(Za + 0);
        float4 a1 = *(const float4*)(Za + 4);
        float4 a2 = *(const float4*)(Za + 8);
        float4 a3 = *(const float4*)(Za + 12);
        int wc; float sgn;
        if (mode == 0) { wc = c; sgn = c ? -1.f : 1.f; }
        else           { wc = 1 - c; sgn = 1.f; }
        const float* Wa = W + ((size_t)wc * DD + d0 + srow) * DD + kk0 + sch;
        float4 w0 = *(const float4*)(Wa + 0);
        float4 w1 = *(const float4*)(Wa + 4);
        float4 w2 = *(const float4*)(Wa + 8);
        float4 w3 = *(const float4*)(Wa + 12);
        __syncthreads();
        bf16x8 pa0, pa1, pw0, pw1;
        pa0[0]=f2bf(a0.x); pa0[1]=f2bf(a0.y); pa0[2]=f2bf(a0.z); pa0[3]=f2bf(a0.w);
        pa0[4]=f2bf(a1.x); pa0[5]=f2bf(a1.y); pa0[6]=f2bf(a1.z); pa0[7]=f2bf(a1.w);
        pa1[0]=f2bf(a2.x); pa1[1]=f2bf(a2.y); pa1[2]=f2bf(a2.z); pa1[3]=f2bf(a2.w);
        pa1[4]=f2bf(a3.x); pa1[5]=f2bf(a3.y); pa1[6]=f2bf(a3.z); pa1[7]=f2bf(a3.w);
        pw0[0]=f2bf(sgn*w0.x); pw0[1]=f2bf(sgn*w0.y); pw0[2]=f2bf(sgn*w0.z); pw0[3]=f2bf(sgn*w0.w);
        pw0[4]=f2bf(sgn*w1.x); pw0[5]=f2bf(sgn*w1.y); pw0[6]=f2bf(sgn*w1.z); pw0[7]=f2bf(sgn*w1.w);
        pw1[0]=f2bf(sgn*w2.x); pw1[1]=f2bf(sgn*w2.y); pw1[2]=f2bf(sgn*w2.z); pw1[3]=f2bf(sgn*w2.w);
        pw1[4]=f2bf(sgn*w3.x); pw1[5]=f2bf(sgn*w3.y); pw1[6]=f2bf(sgn*w3.z); pw1[7]=f2bf(sgn*w3.w);
        *(bf16x8*)&Al[srow * 40 + sch]     = pa0;
        *(bf16x8*)&Al[srow * 40 + sch + 8] = pa1;
        *(bf16x8*)&Bl[srow * 40 + sch]     = pw0;
        *(bf16x8*)&Bl[srow * 40 + sch + 8] = pw1;
        __syncthreads();
        bf16x8 af[4], bff[4];
#pragma unroll
        for (int mi = 0; mi < 4; ++mi) af[mi] = *(const bf16x8*)&Al[(wm + mi * 16 + lm) * 40 + quad * 8];
#pragma unroll
        for (int nj = 0; nj < 4; ++nj) bff[nj] = *(const bf16x8*)&Bl[(wn + nj * 16 + lm) * 40 + quad * 8];
#pragma unroll
        for (int mi = 0; mi < 4; ++mi)
#pragma unroll
            for (int nj = 0; nj < 4; ++nj)
                acc[mi][nj] = __builtin_amdgcn_mfma_f32_16x16x32_bf16(af[mi], bff[nj], acc[mi][nj], 0, 0, 0);
    }

    const float sval = dout[SCR_SC + 1];
    unsigned short* Q16 = (unsigned short*)(dout + SCR_Q16);
    unsigned short* K16 = (unsigned short*)(dout + SCR_K16);
    float* VRF = dout + SCR_VRF;
    const int bofs = mode ? DD : 0;
#pragma unroll
    for (int mi = 0; mi < 4; ++mi)
#pragma unroll
        for (int r = 0; r < 4; ++r) {
            const int m = n0 + wm + mi * 16 + quad * 4 + r;
#pragma unroll
            for (int nj = 0; nj < 4; ++nj) {
                const int d = d0 + wn + nj * 16 + lm;
                float v = acc[mi][nj][r] + bias[bofs + d];
                const size_t ibd = ((size_t)b * NN + m) * DD + d;
                if (z == 0) Q16[ibd] = (unsigned short)f2bf(v);
                else if (z == 1) K16[ibd] = (unsigned short)f2bf(v);
                else if (z == 2) {
                    VRF[ibd] = v;
                    dout[OFF_UV + ((size_t)(b * 2) * NN + m) * DD + d] = v;
                } else {
                    dout[OFF_EST + ((size_t)(b * 2 + 1) * NN + m) * DD + d] = (1.f - sval) * v;
                }
            }
        }
}

// =====================================================================
// output projection, MFMA bf16 (reads est fp32 from d_out)
// z: 0=real, 1=imag
// =====================================================================
__global__ __launch_bounds__(256) void k_outproj(
    const float* __restrict__ Wp, const float* __restrict__ bp, float* __restrict__ dout)
{
    __shared__ short Al[128 * 40];
    __shared__ short Bl[128 * 40];
    const int z = blockIdx.z;
    const int d0 = blockIdx.x * 128;
    const int b = blockIdx.y >> 4;
    const int n0 = (blockIdx.y & 15) * 128;
    const float* Z = dout + OFF_EST;
    const int mode = z;

    const int t = threadIdx.x, wave = t >> 6, lane = t & 63, quad = lane >> 4, lm = lane & 15;
    const int wm = (wave >> 1) * 64, wn = (wave & 1) * 64;
    const int srow = t >> 1, sch = (t & 1) * 16;

    f32x4 acc[4][4];
#pragma unroll
    for (int i = 0; i < 4; ++i)
#pragma unroll
        for (int j = 0; j < 4; ++j) acc[i][j] = (f32x4){0.f, 0.f, 0.f, 0.f};

    for (int kt = 0; kt < 16; ++kt) {
        const int c = kt >> 3, kk0 = (kt & 7) * 32;
        const float* Za = Z + ((size_t)((b * 2 + c) * NN + n0 + srow)) * DD + kk0 + sch;
        float4 a0 = *(const float4*)(Za + 0);
        float4 a1 = *(const float4*)(Za + 4);
        float4 a2 = *(const float4*)(Za + 8);
        float4 a3 = *(const float4*)(Za + 12);
        int wc; float sgn;
        if (mode == 0) { wc = c; sgn = c ? -1.f : 1.f; }
        else           { wc = 1 - c; sgn = 1.f; }
        const float* Wa = Wp + ((size_t)wc * DD + d0 + srow) * DD + kk0 + sch;
        float4 w0 = *(const float4*)(Wa + 0);
        float4 w1 = *(const float4*)(Wa + 4);
        float4 w2 = *(const float4*)(Wa + 8);
        float4 w3 = *(const float4*)(Wa + 12);
        __syncthreads();
        bf16x8 pa0, pa1, pw0, pw1;
        pa0[0]=f2bf(a0.x); pa0[1]=f2bf(a0.y); pa0[2]=f2bf(a0.z); pa0[3]=f2bf(a0.w);
        pa0[4]=f2bf(a1.x); pa0[5]=f2bf(a1.y); pa0[6]=f2bf(a1.z); pa0[7]=f2bf(a1.w);
        pa1[0]=f2bf(a2.x); pa1[1]=f2bf(a2.y); pa1[2]=f2bf(a2.z); pa1[3]=f2bf(a2.w);
        pa1[4]=f2bf(a3.x); pa1[5]=f2bf(a3.y); pa1[6]=f2bf(a3.z); pa1[7]=f2bf(a3.w);
        pw0[0]=f2bf(sgn*w0.x); pw0[1]=f2bf(sgn*w0.y); pw0[2]=f2bf(sgn*w0.z); pw0[3]=f2bf(sgn*w0.w);
        pw0[4]=f2bf(sgn*w1.x); pw0[5]=f2bf(sgn*w1.y); pw0[6]=f2bf(sgn*w1.z); pw0[7]=f2bf(sgn*w1.w);
        pw1[0]=f2bf(sgn*w2.x); pw1[1]=f2bf(sgn*w2.y); pw1[2]=f2bf(sgn*w2.z); pw1[3]=f2bf(sgn*w2.w);
        pw1[4]=f2bf(sgn*w3.x); pw1[5]=f2bf(sgn*w3.y); pw1[6]=f2bf(sgn*w3.z); pw1[7]=f2bf(sgn*w3.w);
        *(bf16x8*)&Al[srow * 40 + sch]     = pa0;
        *(bf16x8*)&Al[srow * 40 + sch + 8] = pa1;
        *(bf16x8*)&Bl[srow * 40 + sch]     = pw0;
        *(bf16x8*)&Bl[srow * 40 + sch + 8] = pw1;
        __syncthreads();
        bf16x8 af[4], bff[4];
#pragma unroll
        for (int mi = 0; mi < 4; ++mi) af[mi] = *(const bf16x8*)&Al[(wm + mi * 16 + lm) * 40 + quad * 8];
#pragma unroll
        for (int nj = 0; nj < 4; ++nj) bff[nj] = *(const bf16x8*)&Bl[(wn + nj * 16 + lm) * 40 + quad * 8];
#pragma unroll
        for (int mi = 0; mi < 4; ++mi)
#pragma unroll
            for (int nj = 0; nj < 4; ++nj)
                acc[mi][nj] = __builtin_amdgcn_mfma_f32_16x16x32_bf16(af[mi], bff[nj], acc[mi][nj], 0, 0, 0);
    }
    const int bofs = mode ? DD : 0;
#pragma unroll
    for (int mi = 0; mi < 4; ++mi)
#pragma unroll
        for (int r = 0; r < 4; ++r) {
            const int m = n0 + wm + mi * 16 + quad * 4 + r;
#pragma unroll
            for (int nj = 0; nj < 4; ++nj) {
                const int d = d0 + wn + nj * 16 + lm;
                dout[OFF_OUT + ((size_t)(b * 2 + z) * NN + m) * DD + d] =
                    acc[mi][nj][r] + bp[bofs + d];
            }
        }
}

// =====================================================================
// transpose V: VRF [b][n][d] fp32 -> VT16 [b][d][n] bf16
// =====================================================================
__global__ void k_vtrans(float* __restrict__ dout) {
    __shared__ float T[64][65];
    const int b = blockIdx.z;
    const int nb = blockIdx.x * 64, db = blockIdx.y * 64;
    const float* V = dout + SCR_VRF + (size_t)b * NN * DD;
    unsigned short* VT = (unsigned short*)(dout + SCR_VT16) + (size_t)b * DD * NN;
    const int tr = threadIdx.x >> 4, tc = (threadIdx.x & 15) * 4;
#pragma unroll
    for (int p = 0; p < 4; ++p) {
        float4 v = *(const float4*)&V[(size_t)(nb + tr + p * 16) * DD + db + tc];
        T[tr + p * 16][tc + 0] = v.x; T[tr + p * 16][tc + 1] = v.y;
        T[tr + p * 16][tc + 2] = v.z; T[tr + p * 16][tc + 3] = v.w;
    }
    __syncthreads();
#pragma unroll
    for (int p = 0; p < 4; ++p) {
        const int d = tr + p * 16;
        ushort4 o;
        o.x = (unsigned short)f2bf(T[tc + 0][d]);
        o.y = (unsigned short)f2bf(T[tc + 1][d]);
        o.z = (unsigned short)f2bf(T[tc + 2][d]);
        o.w = (unsigned short)f2bf(T[tc + 3][d]);
        *(ushort4*)&VT[(size_t)(db + d) * NN + nb + tc] = o;
    }
}

// =====================================================================
// row squared-norms from the bf16 Q/K (consistent with MFMA operands)
// =====================================================================
__global__ void k_norms(float* __restrict__ dout) {
    const int r = blockIdx.x;
    const unsigned short* src = (const unsigned short*)(dout + (blockIdx.y ? SCR_K16 : SCR_Q16));
    float v = bf2f(src[(size_t)r * DD + threadIdx.x]);
    float p = v * v;
    for (int o = 32; o > 0; o >>= 1) p += __shfl_down(p, o, 64);
    __shared__ float red[4];
    if ((threadIdx.x & 63) == 0) red[threadIdx.x >> 6] = p;
    __syncthreads();
    if (threadIdx.x == 0)
        dout[(blockIdx.y ? SCR_KN : SCR_QN) + r] = red[0] + red[1] + red[2] + red[3];
}

// =====================================================================
// causal scores via MFMA QK^T; w = x^{-tau2} unnormalized -> Qij ch0; row sums -> L
// =====================================================================
__global__ __launch_bounds__(256) void k_scores(const float* __restrict__ tmeas,
                                                float* __restrict__ dout) {
    __shared__ short Al[128 * 40];
    __shared__ short Bl[128 * 40];
    const int b = blockIdx.y, x = blockIdx.x;
    int ti = (int)((sqrtf(8.f * x + 1.f) - 1.f) * 0.5f);
    while ((ti + 1) * (ti + 2) / 2 <= x) ++ti;
    while (ti * (ti + 1) / 2 > x) --ti;
    const int tj = x - ti * (ti + 1) / 2;
    const int i0 = ti * 128, j0 = tj * 128;
    const unsigned short* Q16 = (const unsigned short*)(dout + SCR_Q16) + (size_t)b * NN * DD;
    const unsigned short* K16 = (const unsigned short*)(dout + SCR_K16) + (size_t)b * NN * DD;
    const int t = threadIdx.x, wave = t >> 6, lane = t & 63, quad = lane >> 4, lm = lane & 15;
    const int wm = (wave >> 1) * 64, wn = (wave & 1) * 64;
    const int srow = t >> 1, sch = (t & 1) * 16;

    f32x4 acc[4][4];
#pragma unroll
    for (int i = 0; i < 4; ++i)
#pragma unroll
        for (int j = 0; j < 4; ++j) acc[i][j] = (f32x4){0.f, 0.f, 0.f, 0.f};

    for (int kt = 0; kt < 8; ++kt) {
        const int kk0 = kt * 32;
        const float4 qv0 = *(const float4*)(const void*)(Q16 + (size_t)(i0 + srow) * DD + kk0 + sch);
        const float4 qv1 = *(const float4*)(const void*)(Q16 + (size_t)(i0 + srow) * DD + kk0 + sch + 8);
        const float4 kv0 = *(const float4*)(const void*)(K16 + (size_t)(j0 + srow) * DD + kk0 + sch);
        const float4 kv1 = *(const float4*)(const void*)(K16 + (size_t)(j0 + srow) * DD + kk0 + sch + 8);
        __syncthreads();
        *(float4*)(void*)&Al[srow * 40 + sch]     = qv0;
        *(float4*)(void*)&Al[srow * 40 + sch + 8] = qv1;
        *(float4*)(void*)&Bl[srow * 40 + sch]     = kv0;
        *(float4*)(void*)&Bl[srow * 40 + sch + 8] = kv1;
        __syncthreads();
        bf16x8 af[4], bff[4];
#pragma unroll
        for (int mi = 0; mi < 4; ++mi) af[mi] = *(const bf16x8*)&Al[(wm + mi * 16 + lm) * 40 + quad * 8];
#pragma unroll
        for (int nj = 0; nj < 4; ++nj) bff[nj] = *(const bf16x8*)&Bl[(wn + nj * 16 + lm) * 40 + quad * 8];
#pragma unroll
        for (int mi = 0; mi < 4; ++mi)
#pragma unroll
            for (int nj = 0; nj < 4; ++nj)
                acc[mi][nj] = __builtin_amdgcn_mfma_f32_16x16x32_bf16(af[mi], bff[nj], acc[mi][nj], 0, 0, 0);
    }

    const float tau2 = dout[SCR_SC + 0], ga = dout[SCR_SC + 2], om = dout[SCR_SC + 3];
    float* Qij = dout + OFF_QIJ + (size_t)b * 2 * NN * NN;
    const float* QN_ = dout + SCR_QN + b * NN;
    const float* KN_ = dout + SCR_KN + b * NN;
    float kn[4], tjv[4]; int jj[4];
#pragma unroll
    for (int nj = 0; nj < 4; ++nj) {
        jj[nj] = j0 + wn + nj * 16 + lm;
        kn[nj] = KN_[jj[nj]];
        tjv[nj] = tmeas[jj[nj]];
    }
#pragma unroll
    for (int mi = 0; mi < 4; ++mi)
#pragma unroll
        for (int r = 0; r < 4; ++r) {
            const int i = i0 + wm + mi * 16 + quad * 4 + r;
            const float qni = QN_[i], tqi = tmeas[i];
            float rs = 0.f;
#pragma unroll
            for (int nj = 0; nj < 4; ++nj) {
                float xx = ga + om * fabsf(tqi - tjv[nj]) + qni + kn[nj] - 2.f * acc[mi][nj][r];
                xx = fmaxf(xx, 1e-30f);
                float w = (tau2 == 1.f) ? (1.f / xx) : __expf(-tau2 * __logf(xx));
                if (jj[nj] > i) w = 0.f;
                Qij[(size_t)i * NN + jj[nj]] = w;
                rs += w;
            }
            rs += __shfl_down(rs, 8, 16); rs += __shfl_down(rs, 4, 16);
            rs += __shfl_down(rs, 2, 16); rs += __shfl_down(rs, 1, 16);
            if (lm == 0) atomicAdd(&dout[SCR_L + b * NN + i], rs);
        }
}

// =====================================================================
// est_inner partials: (w @ V) via MFMA, split-K, atomicAdd into est ch0
// =====================================================================
__global__ __launch_bounds__(256) void k_estinner(float* __restrict__ dout) {
    __shared__ short Al[128 * 40];
    __shared__ short Bl[128 * 40];
    const int b = blockIdx.z;
    const int d0 = blockIdx.x * 128;
    int y = blockIdx.y, TI = 0;
    for (;;) { const int nc = (TI + 2) >> 1; if (y < nc) break; y -= nc; ++TI; }
    const int i0 = TI * 128;
    const int kbeg = y * 256;
    const int kend = min(kbeg + 256, (TI + 1) * 128);
    const int nst = (kend - kbeg) >> 5;
    const float* Qij = dout + OFF_QIJ + (size_t)b * 2 * NN * NN;
    const unsigned short* VT = (const unsigned short*)(dout + SCR_VT16) + (size_t)b * DD * NN;

    const int t = threadIdx.x, wave = t >> 6, lane = t & 63, quad = lane >> 4, lm = lane & 15;
    const int wm = (wave >> 1) * 64, wn = (wave & 1) * 64;
    const int srow = t >> 1, sch = (t & 1) * 16;

    f32x4 acc[4][4];
#pragma unroll
    for (int i = 0; i < 4; ++i)
#pragma unroll
        for (int j = 0; j < 4; ++j) acc[i][j] = (f32x4){0.f, 0.f, 0.f, 0.f};

    for (int kt = 0; kt < nst; ++kt) {
        const int kk0 = kbeg + kt * 32;
        const float* Aa = Qij + (size_t)(i0 + srow) * NN + kk0 + sch;
        float4 a0 = *(const float4*)(Aa + 0);
        float4 a1 = *(const float4*)(Aa + 4);
        float4 a2 = *(const float4*)(Aa + 8);
        float4 a3 = *(const float4*)(Aa + 12);
        const float4 bv0 = *(const float4*)(const void*)(VT + (size_t)(d0 + srow) * NN + kk0 + sch);
        const float4 bv1 = *(const float4*)(const void*)(VT + (size_t)(d0 + srow) * NN + kk0 + sch + 8);
        __syncthreads();
        bf16x8 pa0, pa1;
        pa0[0]=f2bf(a0.x); pa0[1]=f2bf(a0.y); pa0[2]=f2bf(a0.z); pa0[3]=f2bf(a0.w);
        pa0[4]=f2bf(a1.x); pa0[5]=f2bf(a1.y); pa0[6]=f2bf(a1.z); pa0[7]=f2bf(a1.w);
        pa1[0]=f2bf(a2.x); pa1[1]=f2bf(a2.y); pa1[2]=f2bf(a2.z); pa1[3]=f2bf(a2.w);
        pa1[4]=f2bf(a3.x); pa1[5]=f2bf(a3.y); pa1[6]=f2bf(a3.z); pa1[7]=f2bf(a3.w);
        *(bf16x8*)&Al[srow * 40 + sch]     = pa0;
        *(bf16x8*)&Al[srow * 40 + sch + 8] = pa1;
        *(float4*)(void*)&Bl[srow * 40 + sch]     = bv0;
        *(float4*)(void*)&Bl[srow * 40 + sch + 8] = bv1;
        __syncthreads();
        bf16x8 af[4], bff[4];
#pragma unroll
        for (int mi = 0; mi < 4; ++mi) af[mi] = *(const bf16x8*)&Al[(wm + mi * 16 + lm) * 40 + quad * 8];
#pragma unroll
        for (int nj = 0; nj < 4; ++nj) bff[nj] = *(const bf16x8*)&Bl[(wn + nj * 16 + lm) * 40 + quad * 8];
#pragma unroll
        for (int mi = 0; mi < 4; ++mi)
#pragma unroll
            for (int nj = 0; nj < 4; ++nj)
                acc[mi][nj] = __builtin_amdgcn_mfma_f32_16x16x32_bf16(af[mi], bff[nj], acc[mi][nj], 0, 0, 0);
    }
    float* EST = dout + OFF_EST + (size_t)(b * 2) * NN * DD;
#pragma unroll
    for (int mi = 0; mi < 4; ++mi)
#pragma unroll
        for (int r = 0; r < 4; ++r) {
            const int i = i0 + wm + mi * 16 + quad * 4 + r;
#pragma unroll
            for (int nj = 0; nj < 4; ++nj) {
                const int d = d0 + wn + nj * 16 + lm;
                atomicAdd(&EST[(size_t)i * DD + d], acc[mi][nj][r]);
            }
        }
}

// est ch0 = (1-s)*Vr + s*acc/L
__global__ void k_blend(float* __restrict__ dout) {
    const int b = blockIdx.y, i = blockIdx.x;
    const float s = dout[SCR_SC + 1];
    const float linv = 1.f / dout[SCR_L + b * NN + i];
    float* e = dout + OFF_EST + ((size_t)(b * 2) * NN + i) * DD + threadIdx.x * 4;
    const float* vr = dout + SCR_VRF + ((size_t)b * NN + i) * DD + threadIdx.x * 4;
    float4 ev = *(float4*)e;
    float4 vv = *(const float4*)vr;
    ev.x = (1.f - s) * vv.x + s * ev.x * linv;
    ev.y = (1.f - s) * vv.y + s * ev.y * linv;
    ev.z = (1.f - s) * vv.z + s * ev.z * linv;
    ev.w = (1.f - s) * vv.w + s * ev.w * linv;
    *(float4*)e = ev;
}

// normalize Q_ij causal rows by 1/l
__global__ void k_norm_qij(float* __restrict__ dout) {
    const int b = blockIdx.z, i = blockIdx.y;
    const int j0 = blockIdx.x * 1024 + threadIdx.x * 4;
    if (j0 > i) return;
    const float linv = 1.f / dout[SCR_L + b * NN + i];
    float* p = dout + OFF_QIJ + (size_t)b * 2 * NN * NN + (size_t)i * NN + j0;
    float4 v = *(float4*)p;
    v.x *= linv; v.y *= linv; v.z *= linv; v.w *= linv;
    *(float4*)p = v;
}

// strictly-upper 128-tiles of Q_ij ch0 -> 0
__global__ void k_fill_upper(float* __restrict__ dout) {
    const int b = blockIdx.y, i = blockIdx.x;
    const int jstart = ((i >> 7) + 1) << 7;
    float* row = dout + OFF_QIJ + (size_t)b * 2 * NN * NN + (size_t)i * NN;
    const float4 z = {0.f, 0.f, 0.f, 0.f};
    for (int j = jstart + threadIdx.x * 4; j < NN; j += 256 * 4)
        *(float4*)&row[j] = z;
}

__global__ void k_zero(float* __restrict__ p, long n) {
    const float4 z = {0.f, 0.f, 0.f, 0.f};
    for (long i = ((long)blockIdx.x * 256 + threadIdx.x) * 4; i < n; i += (long)gridDim.x * 1024)
        *(float4*)&p[i] = z;
}

__global__ void k_ones(float* __restrict__ p, long n) {
    const float4 z = {1.f, 1.f, 1.f, 1.f};
    for (long i = ((long)blockIdx.x * 256 + threadIdx.x) * 4; i < n; i += (long)gridDim.x * 1024)
        *(float4*)&p[i] = z;
}

extern "C" void kernel_launch(void* const* d_in, const int* in_sizes, int n_in,
                              void* d_out, int out_size, void* d_ws, size_t ws_size,
                              hipStream_t stream) {
    const float* Zq = (const float*)d_in[0];
    const float* Zk = (const float*)d_in[1];
    const float* Zv = (const float*)d_in[2];
    const float* tm = (const float*)d_in[3];
    const float* Wq = (const float*)d_in[4];
    const float* bq = (const float*)d_in[5];
    const float* Wk = (const float*)d_in[6];
    const float* bk = (const float*)d_in[7];
    const float* Wv = (const float*)d_in[8];
    const float* bv = (const float*)d_in[9];
    const float* Wp = (const float*)d_in[10];
    const float* bp = (const float*)d_in[11];
    const float* lamOm = (const float*)d_in[13];
    const float* lamGa = (const float*)d_in[14];
    const float* tau = (const float*)d_in[15];
    const float* delta = (const float*)d_in[16];
    const float* lamC = (const float*)d_in[17];
    float* out = (float*)d_out;

    k_prep<<<dim3(1), dim3(256), 0, stream>>>(tau, delta, lamOm, lamGa, lamC, out);
    // zero est ch0 (atomic accumulation target for estinner)
    for (int b = 0; b < BN; ++b)
        k_zero<<<dim3(512), dim3(256), 0, stream>>>(
            out + OFF_EST + (size_t)(2 * b) * NN * DD, (long)NN * DD);
    k_qkv<<<dim3(2, 64, 4), dim3(256), 0, stream>>>(Zq, Zk, Zv, Wq, bq, Wk, bk, Wv, bv, out);
    k_norms<<<dim3(8192, 2), dim3(256), 0, stream>>>(out);
    k_vtrans<<<dim3(32, 4, 4), dim3(256), 0, stream>>>(out);
    k_scores<<<dim3(136, 4), dim3(256), 0, stream>>>(tm, out);
    k_estinner<<<dim3(2, 72, 4), dim3(256), 0, stream>>>(out);
    k_blend<<<dim3(2048, 4), dim3(64), 0, stream>>>(out);
    k_norm_qij<<<dim3(2, 2048, 4), dim3(256), 0, stream>>>(out);
    k_outproj<<<dim3(2, 64, 2), dim3(256), 0, stream>>>(Wp, bp, out);
    k_fill_upper<<<dim3(2048, 4), dim3(256), 0, stream>>>(out);
    // dead scratch (Q_ij imaginary channels) -> structural zeros
    for (int b = 0; b < BN; ++b)
        k_zero<<<dim3(4096), dim3(256), 0, stream>>>(
            out + OFF_QIJ + (size_t)(2 * b + 1) * NN * NN, (long)NN * NN);
    k_ones<<<dim3(512), dim3(256), 0, stream>>>(out + OFF_VV, (long)NN * DD);
    k_zero<<<dim3(512), dim3(256), 0, stream>>>(out + OFF_VV + (size_t)NN * DD, (long)NN * DD);
    for (int b = 0; b < BN; ++b)
        k_zero<<<dim3(512), dim3(256), 0, stream>>>(
            out + OFF_UV + (size_t)(2 * b + 1) * NN * DD, (long)NN * DD);
    k_zero<<<dim3(1), dim3(256), 0, stream>>>(out + OFF_LH, 512);
}

// Round 3
// 368.942 us; speedup vs baseline: 1.8896x; 1.1213x over previous
//
#include <hip/hip_runtime.h>
#include <math.h>

#define BN 4
#define NN 2048
#define DD 256
#define EPSF 1e-5f

typedef __attribute__((ext_vector_type(8))) short bf16x8;
typedef __attribute__((ext_vector_type(4))) float f32x4;

// ---- output layout (float offsets) ----
constexpr size_t OFF_EST = 0;                                  // (B,2,N,D)
constexpr size_t OFF_OUT = (size_t)BN * 2 * NN * DD;           // (B,2,N,D)
constexpr size_t OFF_QIJ = OFF_OUT + (size_t)BN * 2 * NN * DD; // (B,2,N,N)
constexpr size_t OFF_VV  = OFF_QIJ + (size_t)BN * 2 * NN * NN; // (1,2,N,D)
constexpr size_t OFF_UV  = OFF_VV + (size_t)2 * NN * DD;       // (B,2,N,D)
constexpr size_t OFF_LH  = OFF_UV + (size_t)BN * 2 * NN * DD;  // (2,D,1)

// ---- scratch in the four Q_ij imaginary-channel regions (zeroed last) ----
// region b0-imag: Q16, K16, VT16 (bf16) + QN/KN/L/SC (fp32)
constexpr size_t SCR_B0   = OFF_QIJ + (size_t)NN * NN;          // float offset of region
constexpr size_t U_Q16    = 0;                                  // ushort offsets in B0
constexpr size_t U_K16    = (size_t)BN * NN * DD;
constexpr size_t U_VT16   = 2 * (size_t)BN * NN * DD;
constexpr size_t SCR_QN   = SCR_B0 + 3 * (size_t)BN * NN * DD / 2; // float offset
constexpr size_t SCR_KN   = SCR_QN + (size_t)BN * NN;
constexpr size_t SCR_L    = SCR_KN + (size_t)BN * NN;
constexpr size_t SCR_SC   = SCR_L + (size_t)BN * NN;            // [tau2, s, ga_bar, om_bar]
// region b1-imag: E16 bf16 [b][n][512] (est concat for outproj)
constexpr size_t SCR_E16F = OFF_QIJ + 3 * (size_t)NN * NN;
// region b2-imag: Zq16, Zk16 bf16 [b][n][512]
constexpr size_t SCR_Z16F = OFF_QIJ + 5 * (size_t)NN * NN;
// region b3-imag: Zv16 + W16 (6 mats [d][512])
constexpr size_t SCR_Z16VF = OFF_QIJ + 7 * (size_t)NN * NN;
constexpr size_t U_W16    = (size_t)BN * NN * 512;              // ushort ofs in b3 region

__device__ __forceinline__ short f2bf(float x) {
    union { float f; unsigned u; } v; v.f = x;
    unsigned r = v.u + 0x7fff + ((v.u >> 16) & 1);
    return (short)(r >> 16);
}
__device__ __forceinline__ float bf2f(unsigned short h) {
    union { unsigned u; float f; } v; v.u = ((unsigned)h) << 16;
    return v.f;
}
__device__ __forceinline__ unsigned short* u16p(float* d, size_t fofs) {
    return (unsigned short*)(d + fofs);
}
__device__ __forceinline__ const unsigned short* u16pc(const float* d, size_t fofs) {
    return (const unsigned short*)(d + fofs);
}

// =====================================================================
// prep: scalars + zero QN/KN/L accumulators
// =====================================================================
__global__ void k_prep(const float* __restrict__ tau, const float* __restrict__ delta,
                       const float* __restrict__ lamOm, const float* __restrict__ lamGa,
                       const float* __restrict__ lamC, float* __restrict__ dout) {
    __shared__ float red[8];
    const int t = threadIdx.x;
    float c2 = lamC[t] * lamC[t];
    float ga = c2 * (lamGa[t] * lamGa[t] + EPSF);
    float om = c2 * (lamOm[t] * lamOm[t] + EPSF);
    for (int o = 32; o > 0; o >>= 1) {
        ga += __shfl_down(ga, o, 64);
        om += __shfl_down(om, o, 64);
    }
    if ((t & 63) == 0) { red[t >> 6] = ga; red[4 + (t >> 6)] = om; }
    __syncthreads();
    if (t == 0) {
        float gs = red[0] + red[1] + red[2] + red[3];
        float os = red[4] + red[5] + red[6] + red[7];
        float* scal = dout + SCR_SC;
        scal[0] = tau[0] * tau[0];
        scal[1] = 1.f / (1.f + __expf(-delta[0]));
        scal[2] = gs / 256.f;
        scal[3] = os / 256.f;
    }
    float* Z = dout + SCR_QN;  // QN,KN,L contiguous
    for (int i = t; i < 3 * BN * NN; i += 256) Z[i] = 0.f;
}

// zero est ch0 (atomic target)
__global__ void k_zero_est(float* __restrict__ dout) {
    const int b = blockIdx.y;
    float* p = dout + OFF_EST + (size_t)(2 * b) * NN * DD;
    const size_t i = ((size_t)blockIdx.x * 256 + threadIdx.x) * 4;
    *(float4*)&p[i] = (float4){0.f, 0.f, 0.f, 0.f};
}

// =====================================================================
// one-time conversions: Z -> bf16 [b][n][512]; weights -> 6 bf16 mats [d][512]
// mats: 0=Wq m0, 1=Wk m0, 2=Wv m0, 3=Wv m1, 4=Wp m0, 5=Wp m1
// m0 row: [Wr | -Wi], m1 row: [Wi | Wr]
// =====================================================================
__global__ void k_cvt(const float* __restrict__ Zq, const float* __restrict__ Zk,
                      const float* __restrict__ Zv,
                      const float* __restrict__ Wq, const float* __restrict__ Wk,
                      const float* __restrict__ Wv, const float* __restrict__ Wp,
                      float* __restrict__ dout) {
    const int z = blockIdx.z;
    if (z < 3) {
        const float* Z = (z == 0) ? Zq : (z == 1) ? Zk : Zv;
        unsigned short* O = (z == 0) ? u16p(dout, SCR_Z16F)
                          : (z == 1) ? u16p(dout, SCR_Z16F) + (size_t)BN * NN * 512
                                     : u16p(dout, SCR_Z16VF);
        const long n4 = (long)BN * 2 * NN * DD / 4;
        for (long i4 = (long)blockIdx.x * 256 + threadIdx.x; i4 < n4;
             i4 += (long)gridDim.x * 256) {
            const long i = i4 * 4;
            const int d = (int)(i & (DD - 1));
            const long r = i >> 8;
            const int n = (int)(r & (NN - 1));
            const long bc = r >> 11;
            const int c = (int)(bc & 1), b = (int)(bc >> 1);
            float4 v = *(const float4*)&Z[i];
            ushort4 o;
            o.x = (unsigned short)f2bf(v.x); o.y = (unsigned short)f2bf(v.y);
            o.z = (unsigned short)f2bf(v.z); o.w = (unsigned short)f2bf(v.w);
            *(ushort4*)&O[((size_t)(b * NN + n)) * 512 + c * 256 + d] = o;
        }
    } else {
        const float* Ws[4] = {Wq, Wk, Wv, Wp};
        unsigned short* W16 = u16p(dout, SCR_Z16VF) + U_W16;
        const long n4 = 6L * 256 * 512 / 4;
        for (long e4 = (long)blockIdx.x * 256 + threadIdx.x; e4 < n4;
             e4 += (long)gridDim.x * 256) {
            const long e = e4 * 4;
            const int k = (int)(e & 511);
            const long rest = e >> 9;
            const int dd = (int)(rest & 255);
            const int m = (int)(rest >> 8);
            int proj, mode;
            if (m < 3)      { proj = m; mode = 0; }
            else if (m == 3){ proj = 2; mode = 1; }
            else            { proj = 3; mode = m - 4; }
            const int kc = k >> 8, kk = k & 255;
            int wc; float sgn;
            if (mode == 0) { wc = kc; sgn = kc ? -1.f : 1.f; }
            else           { wc = 1 - kc; sgn = 1.f; }
            float4 v = *(const float4*)&Ws[proj][((size_t)wc * DD + dd) * DD + kk];
            ushort4 o;
            o.x = (unsigned short)f2bf(sgn * v.x); o.y = (unsigned short)f2bf(sgn * v.y);
            o.z = (unsigned short)f2bf(sgn * v.z); o.w = (unsigned short)f2bf(sgn * v.w);
            *(ushort4*)&W16[(size_t)m * 256 * 512 + (size_t)dd * 512 + k] = o;
        }
    }
}

// =====================================================================
// QKV projection, MFMA bf16, pure-bf16 staging. Fused row-norm atomics.
// z: 0=Qr->Q16(+QN), 1=Kr->K16(+KN), 2=Vr->UVch0, 3=Vi->est ch1 + E16 ch1
// =====================================================================
__global__ __launch_bounds__(256) void k_qkv(const float* __restrict__ bq,
                                             const float* __restrict__ bk,
                                             const float* __restrict__ bv,
                                             float* __restrict__ dout)
{
    __shared__ short Al[128 * 40];
    __shared__ short Bl[128 * 40];
    const int z = blockIdx.z;
    const int d0 = blockIdx.x * 128;
    const int b = blockIdx.y >> 4;
    const int n0 = (blockIdx.y & 15) * 128;

    const unsigned short* Z16 =
        (z == 0) ? u16pc(dout, SCR_Z16F)
      : (z == 1) ? u16pc(dout, SCR_Z16F) + (size_t)BN * NN * 512
                 : u16pc(dout, SCR_Z16VF);
    const unsigned short* W16 = u16pc(dout, SCR_Z16VF) + U_W16 + (size_t)z * 256 * 512;
    const float* bias = (z == 0) ? bq : (z == 1) ? bk : bv;
    const int bofs = (z == 3) ? DD : 0;

    const int t = threadIdx.x, wave = t >> 6, lane = t & 63, quad = lane >> 4, lm = lane & 15;
    const int wm = (wave >> 1) * 64, wn = (wave & 1) * 64;
    const int srow = t >> 1, sch = (t & 1) * 16;

    f32x4 acc[4][4];
#pragma unroll
    for (int i = 0; i < 4; ++i)
#pragma unroll
        for (int j = 0; j < 4; ++j) acc[i][j] = (f32x4){0.f, 0.f, 0.f, 0.f};

    for (int kt = 0; kt < 16; ++kt) {
        const int kk0 = kt * 32;
        const unsigned short* Za = Z16 + ((size_t)(b * NN + n0 + srow)) * 512 + kk0 + sch;
        bf16x8 a0 = *(const bf16x8*)(Za + 0);
        bf16x8 a1 = *(const bf16x8*)(Za + 8);
        const unsigned short* Wa = W16 + (size_t)(d0 + srow) * 512 + kk0 + sch;
        bf16x8 w0 = *(const bf16x8*)(Wa + 0);
        bf16x8 w1 = *(const bf16x8*)(Wa + 8);
        __syncthreads();
        *(bf16x8*)&Al[srow * 40 + sch]     = a0;
        *(bf16x8*)&Al[srow * 40 + sch + 8] = a1;
        *(bf16x8*)&Bl[srow * 40 + sch]     = w0;
        *(bf16x8*)&Bl[srow * 40 + sch + 8] = w1;
        __syncthreads();
        bf16x8 af[4], bff[4];
#pragma unroll
        for (int mi = 0; mi < 4; ++mi) af[mi] = *(const bf16x8*)&Al[(wm + mi * 16 + lm) * 40 + quad * 8];
#pragma unroll
        for (int nj = 0; nj < 4; ++nj) bff[nj] = *(const bf16x8*)&Bl[(wn + nj * 16 + lm) * 40 + quad * 8];
#pragma unroll
        for (int mi = 0; mi < 4; ++mi)
#pragma unroll
            for (int nj = 0; nj < 4; ++nj)
                acc[mi][nj] = __builtin_amdgcn_mfma_f32_16x16x32_bf16(af[mi], bff[nj], acc[mi][nj], 0, 0, 0);
    }

    if (z <= 1) {
        unsigned short* O16 = u16p(dout, SCR_B0) + (z ? U_K16 : U_Q16) + (size_t)b * NN * DD;
        float* NRM = dout + (z ? SCR_KN : SCR_QN) + b * NN;
#pragma unroll
        for (int mi = 0; mi < 4; ++mi)
#pragma unroll
            for (int r = 0; r < 4; ++r) {
                const int m = n0 + wm + mi * 16 + quad * 4 + r;
                float ss = 0.f;
#pragma unroll
                for (int nj = 0; nj < 4; ++nj) {
                    const int d = d0 + wn + nj * 16 + lm;
                    unsigned short h = (unsigned short)f2bf(acc[mi][nj][r] + bias[d]);
                    O16[(size_t)m * DD + d] = h;
                    const float vb = bf2f(h);
                    ss = fmaf(vb, vb, ss);
                }
                ss += __shfl_down(ss, 8, 16); ss += __shfl_down(ss, 4, 16);
                ss += __shfl_down(ss, 2, 16); ss += __shfl_down(ss, 1, 16);
                if (lm == 0) atomicAdd(&NRM[m], ss);
            }
    } else if (z == 2) {
        float* UV0 = dout + OFF_UV + (size_t)(b * 2) * NN * DD;
#pragma unroll
        for (int mi = 0; mi < 4; ++mi)
#pragma unroll
            for (int r = 0; r < 4; ++r) {
                const int m = n0 + wm + mi * 16 + quad * 4 + r;
#pragma unroll
                for (int nj = 0; nj < 4; ++nj) {
                    const int d = d0 + wn + nj * 16 + lm;
                    UV0[(size_t)m * DD + d] = acc[mi][nj][r] + bias[d];
                }
            }
    } else {
        const float s1 = 1.f - dout[SCR_SC + 1];
        float* EST1 = dout + OFF_EST + (size_t)(b * 2 + 1) * NN * DD;
        unsigned short* E16 = u16p(dout, SCR_E16F) + (size_t)b * NN * 512;
#pragma unroll
        for (int mi = 0; mi < 4; ++mi)
#pragma unroll
            for (int r = 0; r < 4; ++r) {
                const int m = n0 + wm + mi * 16 + quad * 4 + r;
#pragma unroll
                for (int nj = 0; nj < 4; ++nj) {
                    const int d = d0 + wn + nj * 16 + lm;
                    const float v = s1 * (acc[mi][nj][r] + bias[bofs + d]);
                    EST1[(size_t)m * DD + d] = v;
                    E16[(size_t)m * 512 + 256 + d] = (unsigned short)f2bf(v);
                }
            }
    }
}

// =====================================================================
// output projection, MFMA bf16, A from E16 (bf16 [b][n][512])
// =====================================================================
__global__ __launch_bounds__(256) void k_outproj(const float* __restrict__ bp,
                                                 float* __restrict__ dout)
{
    __shared__ short Al[128 * 40];
    __shared__ short Bl[128 * 40];
    const int z = blockIdx.z;
    const int d0 = blockIdx.x * 128;
    const int b = blockIdx.y >> 4;
    const int n0 = (blockIdx.y & 15) * 128;
    const unsigned short* E16 = u16pc(dout, SCR_E16F) + (size_t)b * NN * 512;
    const unsigned short* W16 = u16pc(dout, SCR_Z16VF) + U_W16 + (size_t)(4 + z) * 256 * 512;

    const int t = threadIdx.x, wave = t >> 6, lane = t & 63, quad = lane >> 4, lm = lane & 15;
    const int wm = (wave >> 1) * 64, wn = (wave & 1) * 64;
    const int srow = t >> 1, sch = (t & 1) * 16;

    f32x4 acc[4][4];
#pragma unroll
    for (int i = 0; i < 4; ++i)
#pragma unroll
        for (int j = 0; j < 4; ++j) acc[i][j] = (f32x4){0.f, 0.f, 0.f, 0.f};

    for (int kt = 0; kt < 16; ++kt) {
        const int kk0 = kt * 32;
        const unsigned short* Za = E16 + ((size_t)(n0 + srow)) * 512 + kk0 + sch;
        bf16x8 a0 = *(const bf16x8*)(Za + 0);
        bf16x8 a1 = *(const bf16x8*)(Za + 8);
        const unsigned short* Wa = W16 + (size_t)(d0 + srow) * 512 + kk0 + sch;
        bf16x8 w0 = *(const bf16x8*)(Wa + 0);
        bf16x8 w1 = *(const bf16x8*)(Wa + 8);
        __syncthreads();
        *(bf16x8*)&Al[srow * 40 + sch]     = a0;
        *(bf16x8*)&Al[srow * 40 + sch + 8] = a1;
        *(bf16x8*)&Bl[srow * 40 + sch]     = w0;
        *(bf16x8*)&Bl[srow * 40 + sch + 8] = w1;
        __syncthreads();
        bf16x8 af[4], bff[4];
#pragma unroll
        for (int mi = 0; mi < 4; ++mi) af[mi] = *(const bf16x8*)&Al[(wm + mi * 16 + lm) * 40 + quad * 8];
#pragma unroll
        for (int nj = 0; nj < 4; ++nj) bff[nj] = *(const bf16x8*)&Bl[(wn + nj * 16 + lm) * 40 + quad * 8];
#pragma unroll
        for (int mi = 0; mi < 4; ++mi)
#pragma unroll
            for (int nj = 0; nj < 4; ++nj)
                acc[mi][nj] = __builtin_amdgcn_mfma_f32_16x16x32_bf16(af[mi], bff[nj], acc[mi][nj], 0, 0, 0);
    }
    const int bofs = z ? DD : 0;
    float* O = dout + OFF_OUT + (size_t)(b * 2 + z) * NN * DD;
#pragma unroll
    for (int mi = 0; mi < 4; ++mi)
#pragma unroll
        for (int r = 0; r < 4; ++r) {
            const int m = n0 + wm + mi * 16 + quad * 4 + r;
#pragma unroll
            for (int nj = 0; nj < 4; ++nj) {
                const int d = d0 + wn + nj * 16 + lm;
                O[(size_t)m * DD + d] = acc[mi][nj][r] + bp[bofs + d];
            }
        }
}

// =====================================================================
// transpose V: UV ch0 [b][n][d] fp32 -> VT16 [b][d][n] bf16
// =====================================================================
__global__ void k_vtrans(float* __restrict__ dout) {
    __shared__ float T[64][65];
    const int b = blockIdx.z;
    const int nb = blockIdx.x * 64, db = blockIdx.y * 64;
    const float* V = dout + OFF_UV + (size_t)(b * 2) * NN * DD;
    unsigned short* VT = u16p(dout, SCR_B0) + U_VT16 + (size_t)b * DD * NN;
    const int tr = threadIdx.x >> 4, tc = (threadIdx.x & 15) * 4;
#pragma unroll
    for (int p = 0; p < 4; ++p) {
        float4 v = *(const float4*)&V[(size_t)(nb + tr + p * 16) * DD + db + tc];
        T[tr + p * 16][tc + 0] = v.x; T[tr + p * 16][tc + 1] = v.y;
        T[tr + p * 16][tc + 2] = v.z; T[tr + p * 16][tc + 3] = v.w;
    }
    __syncthreads();
#pragma unroll
    for (int p = 0; p < 4; ++p) {
        const int d = tr + p * 16;
        ushort4 o;
        o.x = (unsigned short)f2bf(T[tc + 0][d]);
        o.y = (unsigned short)f2bf(T[tc + 1][d]);
        o.z = (unsigned short)f2bf(T[tc + 2][d]);
        o.w = (unsigned short)f2bf(T[tc + 3][d]);
        *(ushort4*)&VT[(size_t)(db + d) * NN + nb + tc] = o;
    }
}

// =====================================================================
// causal scores via MFMA QK^T; w = x^{-tau2} unnormalized -> Qij ch0; row sums -> L
// =====================================================================
__global__ __launch_bounds__(256) void k_scores(const float* __restrict__ tmeas,
                                                float* __restrict__ dout) {
    __shared__ short Al[128 * 40];
    __shared__ short Bl[128 * 40];
    const int b = blockIdx.y, x = blockIdx.x;
    int ti = (int)((sqrtf(8.f * x + 1.f) - 1.f) * 0.5f);
    while ((ti + 1) * (ti + 2) / 2 <= x) ++ti;
    while (ti * (ti + 1) / 2 > x) --ti;
    const int tj = x - ti * (ti + 1) / 2;
    const int i0 = ti * 128, j0 = tj * 128;
    const unsigned short* Q16 = u16pc(dout, SCR_B0) + U_Q16 + (size_t)b * NN * DD;
    const unsigned short* K16 = u16pc(dout, SCR_B0) + U_K16 + (size_t)b * NN * DD;
    const int t = threadIdx.x, wave = t >> 6, lane = t & 63, quad = lane >> 4, lm = lane & 15;
    const int wm = (wave >> 1) * 64, wn = (wave & 1) * 64;
    const int srow = t >> 1, sch = (t & 1) * 16;

    f32x4 acc[4][4];
#pragma unroll
    for (int i = 0; i < 4; ++i)
#pragma unroll
        for (int j = 0; j < 4; ++j) acc[i][j] = (f32x4){0.f, 0.f, 0.f, 0.f};

    for (int kt = 0; kt < 8; ++kt) {
        const int kk0 = kt * 32;
        bf16x8 q0 = *(const bf16x8*)(Q16 + (size_t)(i0 + srow) * DD + kk0 + sch);
        bf16x8 q1 = *(const bf16x8*)(Q16 + (size_t)(i0 + srow) * DD + kk0 + sch + 8);
        bf16x8 k0 = *(const bf16x8*)(K16 + (size_t)(j0 + srow) * DD + kk0 + sch);
        bf16x8 k1 = *(const bf16x8*)(K16 + (size_t)(j0 + srow) * DD + kk0 + sch + 8);
        __syncthreads();
        *(bf16x8*)&Al[srow * 40 + sch]     = q0;
        *(bf16x8*)&Al[srow * 40 + sch + 8] = q1;
        *(bf16x8*)&Bl[srow * 40 + sch]     = k0;
        *(bf16x8*)&Bl[srow * 40 + sch + 8] = k1;
        __syncthreads();
        bf16x8 af[4], bff[4];
#pragma unroll
        for (int mi = 0; mi < 4; ++mi) af[mi] = *(const bf16x8*)&Al[(wm + mi * 16 + lm) * 40 + quad * 8];
#pragma unroll
        for (int nj = 0; nj < 4; ++nj) bff[nj] = *(const bf16x8*)&Bl[(wn + nj * 16 + lm) * 40 + quad * 8];
#pragma unroll
        for (int mi = 0; mi < 4; ++mi)
#pragma unroll
            for (int nj = 0; nj < 4; ++nj)
                acc[mi][nj] = __builtin_amdgcn_mfma_f32_16x16x32_bf16(af[mi], bff[nj], acc[mi][nj], 0, 0, 0);
    }

    const float tau2 = dout[SCR_SC + 0], ga = dout[SCR_SC + 2], om = dout[SCR_SC + 3];
    float* Qij = dout + OFF_QIJ + (size_t)b * 2 * NN * NN;
    const float* QN_ = dout + SCR_QN + b * NN;
    const float* KN_ = dout + SCR_KN + b * NN;
    float kn[4], tjv[4]; int jj[4];
#pragma unroll
    for (int nj = 0; nj < 4; ++nj) {
        jj[nj] = j0 + wn + nj * 16 + lm;
        kn[nj] = KN_[jj[nj]];
        tjv[nj] = tmeas[jj[nj]];
    }
#pragma unroll
    for (int mi = 0; mi < 4; ++mi)
#pragma unroll
        for (int r = 0; r < 4; ++r) {
            const int i = i0 + wm + mi * 16 + quad * 4 + r;
            const float qni = QN_[i], tqi = tmeas[i];
            float rs = 0.f;
#pragma unroll
            for (int nj = 0; nj < 4; ++nj) {
                float xx = ga + om * fabsf(tqi - tjv[nj]) + qni + kn[nj] - 2.f * acc[mi][nj][r];
                xx = fmaxf(xx, 1e-30f);
                float w = (tau2 == 1.f) ? (1.f / xx) : __expf(-tau2 * __logf(xx));
                if (jj[nj] > i) w = 0.f;
                Qij[(size_t)i * NN + jj[nj]] = w;
                rs += w;
            }
            rs += __shfl_down(rs, 8, 16); rs += __shfl_down(rs, 4, 16);
            rs += __shfl_down(rs, 2, 16); rs += __shfl_down(rs, 1, 16);
            if (lm == 0) atomicAdd(&dout[SCR_L + b * NN + i], rs);
        }
}

// =====================================================================
// est_inner: A=(w/l) (normalized in-flight, written back to Qij), B=V^T bf16
// full-D (256 cols), 8 waves, split-K chunks of 256; atomicAdd into est ch0
// =====================================================================
__global__ __launch_bounds__(512) void k_estinner(float* __restrict__ dout) {
    __shared__ short Al[128 * 40];   // 10 KB
    __shared__ short Bl[256 * 40];   // 20 KB
    const int b = blockIdx.y;
    int y = blockIdx.x, TI = 0;
    for (;;) { const int nc = (TI + 2) >> 1; if (y < nc) break; y -= nc; ++TI; }
    const int i0 = TI * 128;
    const int kbeg = y * 256;
    const int kend = min(kbeg + 256, (TI + 1) * 128);
    const int nst = (kend - kbeg) >> 5;
    float* Qij = dout + OFF_QIJ + (size_t)b * 2 * NN * NN;
    const unsigned short* VT = u16pc(dout, SCR_B0) + U_VT16 + (size_t)b * DD * NN;

    const int t = threadIdx.x, wave = t >> 6, lane = t & 63, quad = lane >> 4, lm = lane & 15;
    const int wm = (wave >> 2) * 64, wn = (wave & 3) * 64;
    const int arow = t >> 2, acol = (t & 3) * 8;    // A staging: 128 rows x 8 floats
    const int vrow = t >> 1, vcol = (t & 1) * 16;   // B staging: 256 rows x 16 bf16
    const float linv = 1.f / dout[SCR_L + b * NN + i0 + arow];

    f32x4 acc[4][4];
#pragma unroll
    for (int i = 0; i < 4; ++i)
#pragma unroll
        for (int j = 0; j < 4; ++j) acc[i][j] = (f32x4){0.f, 0.f, 0.f, 0.f};

    for (int kt = 0; kt < nst; ++kt) {
        const int kk0 = kbeg + kt * 32;
        float* Ap = &Qij[(size_t)(i0 + arow) * NN + kk0 + acol];
        float4 w0 = *(const float4*)(Ap + 0);
        float4 w1 = *(const float4*)(Ap + 4);
        w0.x *= linv; w0.y *= linv; w0.z *= linv; w0.w *= linv;
        w1.x *= linv; w1.y *= linv; w1.z *= linv; w1.w *= linv;
        bf16x8 pa;
        pa[0] = f2bf(w0.x); pa[1] = f2bf(w0.y); pa[2] = f2bf(w0.z); pa[3] = f2bf(w0.w);
        pa[4] = f2bf(w1.x); pa[5] = f2bf(w1.y); pa[6] = f2bf(w1.z); pa[7] = f2bf(w1.w);
        bf16x8 v0 = *(const bf16x8*)(VT + (size_t)vrow * NN + kk0 + vcol);
        bf16x8 v1 = *(const bf16x8*)(VT + (size_t)vrow * NN + kk0 + vcol + 8);
        *(float4*)(Ap + 0) = w0;   // normalized write-back (sole owner of this range)
        *(float4*)(Ap + 4) = w1;
        __syncthreads();
        *(bf16x8*)&Al[arow * 40 + acol] = pa;
        *(bf16x8*)&Bl[vrow * 40 + vcol]     = v0;
        *(bf16x8*)&Bl[vrow * 40 + vcol + 8] = v1;
        __syncthreads();
        bf16x8 af[4], bff[4];
#pragma unroll
        for (int mi = 0; mi < 4; ++mi) af[mi] = *(const bf16x8*)&Al[(wm + mi * 16 + lm) * 40 + quad * 8];
#pragma unroll
        for (int nj = 0; nj < 4; ++nj) bff[nj] = *(const bf16x8*)&Bl[(wn + nj * 16 + lm) * 40 + quad * 8];
#pragma unroll
        for (int mi = 0; mi < 4; ++mi)
#pragma unroll
            for (int nj = 0; nj < 4; ++nj)
                acc[mi][nj] = __builtin_amdgcn_mfma_f32_16x16x32_bf16(af[mi], bff[nj], acc[mi][nj], 0, 0, 0);
    }
    float* EST = dout + OFF_EST + (size_t)(b * 2) * NN * DD;
#pragma unroll
    for (int mi = 0; mi < 4; ++mi)
#pragma unroll
        for (int r = 0; r < 4; ++r) {
            const int i = i0 + wm + mi * 16 + quad * 4 + r;
#pragma unroll
            for (int nj = 0; nj < 4; ++nj) {
                const int d = wn + nj * 16 + lm;
                atomicAdd(&EST[(size_t)i * DD + d], acc[mi][nj][r]);
            }
        }
}

// est ch0 = (1-s)*Vr + s*acc (acc already normalized); also emit E16 ch0 bf16
__global__ void k_blend(float* __restrict__ dout) {
    const int b = blockIdx.y, i = blockIdx.x;
    const float s = dout[SCR_SC + 1];
    float* e = dout + OFF_EST + ((size_t)(b * 2) * NN + i) * DD + threadIdx.x * 4;
    const float* vr = dout + OFF_UV + ((size_t)(b * 2) * NN + i) * DD + threadIdx.x * 4;
    unsigned short* E16 = u16p(dout, SCR_E16F) + ((size_t)(b * NN + i)) * 512 + threadIdx.x * 4;
    float4 ev = *(float4*)e;
    float4 vv = *(const float4*)vr;
    ev.x = (1.f - s) * vv.x + s * ev.x;
    ev.y = (1.f - s) * vv.y + s * ev.y;
    ev.z = (1.f - s) * vv.z + s * ev.z;
    ev.w = (1.f - s) * vv.w + s * ev.w;
    *(float4*)e = ev;
    ushort4 o;
    o.x = (unsigned short)f2bf(ev.x); o.y = (unsigned short)f2bf(ev.y);
    o.z = (unsigned short)f2bf(ev.z); o.w = (unsigned short)f2bf(ev.w);
    *(ushort4*)E16 = o;
}

// =====================================================================
// all structural fills in one launch. grid (2048, 15)
// z 0..3: Qij imag b -> 0 | z4: VV ch0 -> 1 | z5: VV ch1 -> 0
// z 6..9: UV ch1 b -> 0 | z10: LH -> 0 | z 11..14: Qij ch0 strict-upper -> 0
// =====================================================================
__global__ void k_fills(float* __restrict__ dout) {
    const int z = blockIdx.z;
    if (z >= 11) {
        const int b = z - 11, i = blockIdx.x;
        const int jstart = ((i >> 7) + 1) << 7;
        float* row = dout + OFF_QIJ + (size_t)b * 2 * NN * NN + (size_t)i * NN;
        const float4 zz = {0.f, 0.f, 0.f, 0.f};
        for (int j = jstart + threadIdx.x * 4; j < NN; j += 256 * 4)
            *(float4*)&row[j] = zz;
        return;
    }
    size_t base; long n; float val = 0.f;
    if (z < 4)       { base = OFF_QIJ + (size_t)(2 * z + 1) * NN * NN; n = (long)NN * NN; }
    else if (z == 4) { base = OFF_VV; n = (long)NN * DD; val = 1.f; }
    else if (z == 5) { base = OFF_VV + (size_t)NN * DD; n = (long)NN * DD; }
    else if (z < 10) { base = OFF_UV + (size_t)(2 * (z - 6) + 1) * NN * DD; n = (long)NN * DD; }
    else             { base = OFF_LH; n = 512; }
    float* p = dout + base;
    const float4 v = {val, val, val, val};
    for (long i = ((long)blockIdx.x * 256 + threadIdx.x) * 4; i < n;
         i += (long)gridDim.x * 1024)
        *(float4*)&p[i] = v;
}

extern "C" void kernel_launch(void* const* d_in, const int* in_sizes, int n_in,
                              void* d_out, int out_size, void* d_ws, size_t ws_size,
                              hipStream_t stream) {
    const float* Zq = (const float*)d_in[0];
    const float* Zk = (const float*)d_in[1];
    const float* Zv = (const float*)d_in[2];
    const float* tm = (const float*)d_in[3];
    const float* Wq = (const float*)d_in[4];
    const float* bq = (const float*)d_in[5];
    const float* Wk = (const float*)d_in[6];
    const float* bk = (const float*)d_in[7];
    const float* Wv = (const float*)d_in[8];
    const float* bv = (const float*)d_in[9];
    const float* Wp = (const float*)d_in[10];
    const float* bp = (const float*)d_in[11];
    const float* lamOm = (const float*)d_in[13];
    const float* lamGa = (const float*)d_in[14];
    const float* tau = (const float*)d_in[15];
    const float* delta = (const float*)d_in[16];
    const float* lamC = (const float*)d_in[17];
    float* out = (float*)d_out;

    k_prep<<<dim3(1), dim3(256), 0, stream>>>(tau, delta, lamOm, lamGa, lamC, out);
    k_cvt<<<dim3(2048, 1, 4), dim3(256), 0, stream>>>(Zq, Zk, Zv, Wq, Wk, Wv, Wp, out);
    k_zero_est<<<dim3(512, 4), dim3(256), 0, stream>>>(out);
    k_qkv<<<dim3(2, 64, 4), dim3(256), 0, stream>>>(bq, bk, bv, out);
    k_vtrans<<<dim3(32, 4, 4), dim3(256), 0, stream>>>(out);
    k_scores<<<dim3(136, 4), dim3(256), 0, stream>>>(tm, out);
    k_estinner<<<dim3(72, 4), dim3(512), 0, stream>>>(out);
    k_blend<<<dim3(2048, 4), dim3(64), 0, stream>>>(out);
    k_outproj<<<dim3(2, 64, 2), dim3(256), 0, stream>>>(bp, out);
    k_fills<<<dim3(2048, 1, 15), dim3(256), 0, stream>>>(out);
}

// Round 4
// 354.606 us; speedup vs baseline: 1.9659x; 1.0404x over previous
//
#include <hip/hip_runtime.h>
#include <math.h>

#define BN 4
#define NN 2048
#define DD 256
#define EPSF 1e-5f

typedef __attribute__((ext_vector_type(8))) short bf16x8;
typedef __attribute__((ext_vector_type(4))) float f32x4;

// ---- output layout (float offsets) ----
constexpr size_t OFF_EST = 0;                                  // (B,2,N,D)
constexpr size_t OFF_OUT = (size_t)BN * 2 * NN * DD;           // (B,2,N,D)
constexpr size_t OFF_QIJ = OFF_OUT + (size_t)BN * 2 * NN * DD; // (B,2,N,N)
constexpr size_t OFF_VV  = OFF_QIJ + (size_t)BN * 2 * NN * NN; // (1,2,N,D)
constexpr size_t OFF_UV  = OFF_VV + (size_t)2 * NN * DD;       // (B,2,N,D)
constexpr size_t OFF_LH  = OFF_UV + (size_t)BN * 2 * NN * DD;  // (2,D,1)

// ---- scratch regions (Q_ij imaginary channels; zeroed before return) ----
// b0-imag: Q16 | K16 | VT16 (bf16, 12.6MB) then QN/KN/L/SC/W16P (tail)
constexpr size_t SCR_B0   = OFF_QIJ + (size_t)NN * NN;
constexpr size_t U_Q16    = 0;                         // ushort offsets in b0
constexpr size_t U_K16    = (size_t)BN * NN * DD;      // 2097152
constexpr size_t U_VT16   = 2 * (size_t)BN * NN * DD;  // 4194304
constexpr size_t SCR_QN   = SCR_B0 + 3 * (size_t)BN * NN * DD / 2; // +3145728
constexpr size_t SCR_KN   = SCR_QN + (size_t)BN * NN;
constexpr size_t SCR_L    = SCR_KN + (size_t)BN * NN;
constexpr size_t SCR_SC   = SCR_L + (size_t)BN * NN;   // [tau2, s, ga_bar, om_bar]
constexpr size_t SCR_W16P = SCR_SC + 16;               // 2 outproj mats bf16 (131072 floats)
// b1-imag: E16 bf16 [b][n][512] (8.4MB) | PART bf16 [b][30][128][256] (7.9MB)
constexpr size_t SCR_E16F = OFF_QIJ + 3 * (size_t)NN * NN;
constexpr size_t U_PART   = (size_t)BN * NN * 512;     // ushort ofs in b1
// b2-imag: Zq16, Zk16 bf16 [b][n][512]
constexpr size_t SCR_Z16F = OFF_QIJ + 5 * (size_t)NN * NN;
// b3-imag: Zv16 + W16 qkv (4 mats [d][512])
constexpr size_t SCR_Z16VF = OFF_QIJ + 7 * (size_t)NN * NN;
constexpr size_t U_W16    = (size_t)BN * NN * 512;     // ushort ofs in b3

__device__ __forceinline__ short f2bf(float x) {
    union { float f; unsigned u; } v; v.f = x;
    unsigned r = v.u + 0x7fff + ((v.u >> 16) & 1);
    return (short)(r >> 16);
}
__device__ __forceinline__ float bf2f(unsigned short h) {
    union { unsigned u; float f; } v; v.u = ((unsigned)h) << 16;
    return v.f;
}
__device__ __forceinline__ unsigned short* u16p(float* d, size_t fofs) {
    return (unsigned short*)(d + fofs);
}
__device__ __forceinline__ const unsigned short* u16pc(const float* d, size_t fofs) {
    return (const unsigned short*)(d + fofs);
}
// split-K chunk table (chunk = 768 cols): nc per 128-row tile, prefix base
__device__ __forceinline__ int nc_of(int TI) { return TI >= 12 ? 3 : (TI >= 6 ? 2 : 1); }
__device__ __forceinline__ int cb_of(int TI) {
    return TI < 6 ? TI : (TI < 12 ? 6 + 2 * (TI - 6) : 18 + 3 * (TI - 12));
}

// =====================================================================
// cvt (+ fused prep): z 0..2 = Z tensors -> bf16 [b][n][512]
// z=3: weights -> 6 bf16 mats [d][512] (0..3 -> b3, 4..5 -> b0 tail)
// z=4: scalars + zero QN/KN/L
// =====================================================================
__global__ void k_cvt(const float* __restrict__ Zq, const float* __restrict__ Zk,
                      const float* __restrict__ Zv,
                      const float* __restrict__ Wq, const float* __restrict__ Wk,
                      const float* __restrict__ Wv, const float* __restrict__ Wp,
                      const float* __restrict__ tau, const float* __restrict__ delta,
                      const float* __restrict__ lamOm, const float* __restrict__ lamGa,
                      const float* __restrict__ lamC,
                      float* __restrict__ dout) {
    const int z = blockIdx.z;
    if (z < 3) {
        const float* Z = (z == 0) ? Zq : (z == 1) ? Zk : Zv;
        unsigned short* O = (z == 0) ? u16p(dout, SCR_Z16F)
                          : (z == 1) ? u16p(dout, SCR_Z16F) + (size_t)BN * NN * 512
                                     : u16p(dout, SCR_Z16VF);
        const long n4 = (long)BN * 2 * NN * DD / 4;
        for (long i4 = (long)blockIdx.x * 256 + threadIdx.x; i4 < n4;
             i4 += (long)gridDim.x * 256) {
            const long i = i4 * 4;
            const int d = (int)(i & (DD - 1));
            const long r = i >> 8;
            const int n = (int)(r & (NN - 1));
            const long bc = r >> 11;
            const int c = (int)(bc & 1), b = (int)(bc >> 1);
            float4 v = *(const float4*)&Z[i];
            ushort4 o;
            o.x = (unsigned short)f2bf(v.x); o.y = (unsigned short)f2bf(v.y);
            o.z = (unsigned short)f2bf(v.z); o.w = (unsigned short)f2bf(v.w);
            *(ushort4*)&O[((size_t)(b * NN + n)) * 512 + c * 256 + d] = o;
        }
    } else if (z == 3) {
        const float* Ws[4] = {Wq, Wk, Wv, Wp};
        const long n4 = 6L * 256 * 512 / 4;
        for (long e4 = (long)blockIdx.x * 256 + threadIdx.x; e4 < n4;
             e4 += (long)gridDim.x * 256) {
            const long e = e4 * 4;
            const int k = (int)(e & 511);
            const long rest = e >> 9;
            const int dd = (int)(rest & 255);
            const int m = (int)(rest >> 8);
            int proj, mode;
            if (m < 3)      { proj = m; mode = 0; }
            else if (m == 3){ proj = 2; mode = 1; }
            else            { proj = 3; mode = m - 4; }
            const int kc = k >> 8, kk = k & 255;
            int wc; float sgn;
            if (mode == 0) { wc = kc; sgn = kc ? -1.f : 1.f; }
            else           { wc = 1 - kc; sgn = 1.f; }
            float4 v = *(const float4*)&Ws[proj][((size_t)wc * DD + dd) * DD + kk];
            ushort4 o;
            o.x = (unsigned short)f2bf(sgn * v.x); o.y = (unsigned short)f2bf(sgn * v.y);
            o.z = (unsigned short)f2bf(sgn * v.z); o.w = (unsigned short)f2bf(sgn * v.w);
            unsigned short* dst = (m < 4)
                ? u16p(dout, SCR_Z16VF) + U_W16 + (size_t)m * 131072
                : u16p(dout, SCR_W16P) + (size_t)(m - 4) * 131072;
            *(ushort4*)&dst[(size_t)dd * 512 + k] = o;
        }
    } else {
        // zero QN/KN/L (24576 floats)
        const int idx = blockIdx.x * 256 + threadIdx.x;
        if (idx < 3 * BN * NN) dout[SCR_QN + idx] = 0.f;
        if (blockIdx.x == 0) {
            __shared__ float red[8];
            const int t = threadIdx.x;
            float c2 = lamC[t] * lamC[t];
            float ga = c2 * (lamGa[t] * lamGa[t] + EPSF);
            float om = c2 * (lamOm[t] * lamOm[t] + EPSF);
            for (int o = 32; o > 0; o >>= 1) {
                ga += __shfl_down(ga, o, 64);
                om += __shfl_down(om, o, 64);
            }
            if ((t & 63) == 0) { red[t >> 6] = ga; red[4 + (t >> 6)] = om; }
            __syncthreads();
            if (t == 0) {
                float gs = red[0] + red[1] + red[2] + red[3];
                float os = red[4] + red[5] + red[6] + red[7];
                float* scal = dout + SCR_SC;
                scal[0] = tau[0] * tau[0];
                scal[1] = 1.f / (1.f + __expf(-delta[0]));
                scal[2] = gs / 256.f;
                scal[3] = os / 256.f;
            }
        }
    }
}

// =====================================================================
// QKV projection, MFMA bf16; fused row-norm atomics (Q/K only)
// z: 0=Qr->Q16(+QN), 1=Kr->K16(+KN), 2=Vr->UVch0, 3=Vi->est ch1 + E16 ch1
// =====================================================================
__global__ __launch_bounds__(256) void k_qkv(const float* __restrict__ bq,
                                             const float* __restrict__ bk,
                                             const float* __restrict__ bv,
                                             float* __restrict__ dout)
{
    __shared__ short Al[128 * 40];
    __shared__ short Bl[128 * 40];
    const int z = blockIdx.z;
    const int d0 = blockIdx.x * 128;
    const int b = blockIdx.y >> 4;
    const int n0 = (blockIdx.y & 15) * 128;

    const unsigned short* Z16 =
        (z == 0) ? u16pc(dout, SCR_Z16F)
      : (z == 1) ? u16pc(dout, SCR_Z16F) + (size_t)BN * NN * 512
                 : u16pc(dout, SCR_Z16VF);
    const unsigned short* W16 = u16pc(dout, SCR_Z16VF) + U_W16 + (size_t)z * 131072;
    const float* bias = (z == 0) ? bq : (z == 1) ? bk : bv;
    const int bofs = (z == 3) ? DD : 0;

    const int t = threadIdx.x, wave = t >> 6, lane = t & 63, quad = lane >> 4, lm = lane & 15;
    const int wm = (wave >> 1) * 64, wn = (wave & 1) * 64;
    const int srow = t >> 1, sch = (t & 1) * 16;

    f32x4 acc[4][4];
#pragma unroll
    for (int i = 0; i < 4; ++i)
#pragma unroll
        for (int j = 0; j < 4; ++j) acc[i][j] = (f32x4){0.f, 0.f, 0.f, 0.f};

    for (int kt = 0; kt < 16; ++kt) {
        const int kk0 = kt * 32;
        const unsigned short* Za = Z16 + ((size_t)(b * NN + n0 + srow)) * 512 + kk0 + sch;
        bf16x8 a0 = *(const bf16x8*)(Za + 0);
        bf16x8 a1 = *(const bf16x8*)(Za + 8);
        const unsigned short* Wa = W16 + (size_t)(d0 + srow) * 512 + kk0 + sch;
        bf16x8 w0 = *(const bf16x8*)(Wa + 0);
        bf16x8 w1 = *(const bf16x8*)(Wa + 8);
        __syncthreads();
        *(bf16x8*)&Al[srow * 40 + sch]     = a0;
        *(bf16x8*)&Al[srow * 40 + sch + 8] = a1;
        *(bf16x8*)&Bl[srow * 40 + sch]     = w0;
        *(bf16x8*)&Bl[srow * 40 + sch + 8] = w1;
        __syncthreads();
        bf16x8 af[4], bff[4];
#pragma unroll
        for (int mi = 0; mi < 4; ++mi) af[mi] = *(const bf16x8*)&Al[(wm + mi * 16 + lm) * 40 + quad * 8];
#pragma unroll
        for (int nj = 0; nj < 4; ++nj) bff[nj] = *(const bf16x8*)&Bl[(wn + nj * 16 + lm) * 40 + quad * 8];
#pragma unroll
        for (int mi = 0; mi < 4; ++mi)
#pragma unroll
            for (int nj = 0; nj < 4; ++nj)
                acc[mi][nj] = __builtin_amdgcn_mfma_f32_16x16x32_bf16(af[mi], bff[nj], acc[mi][nj], 0, 0, 0);
    }

    if (z <= 1) {
        unsigned short* O16 = u16p(dout, SCR_B0) + (z ? U_K16 : U_Q16) + (size_t)b * NN * DD;
        float* NRM = dout + (z ? SCR_KN : SCR_QN) + b * NN;
#pragma unroll
        for (int mi = 0; mi < 4; ++mi)
#pragma unroll
            for (int r = 0; r < 4; ++r) {
                const int m = n0 + wm + mi * 16 + quad * 4 + r;
                float ss = 0.f;
#pragma unroll
                for (int nj = 0; nj < 4; ++nj) {
                    const int d = d0 + wn + nj * 16 + lm;
                    unsigned short h = (unsigned short)f2bf(acc[mi][nj][r] + bias[d]);
                    O16[(size_t)m * DD + d] = h;
                    const float vb = bf2f(h);
                    ss = fmaf(vb, vb, ss);
                }
                ss += __shfl_down(ss, 8, 16); ss += __shfl_down(ss, 4, 16);
                ss += __shfl_down(ss, 2, 16); ss += __shfl_down(ss, 1, 16);
                if (lm == 0) atomicAdd(&NRM[m], ss);
            }
    } else if (z == 2) {
        float* UV0 = dout + OFF_UV + (size_t)(b * 2) * NN * DD;
#pragma unroll
        for (int mi = 0; mi < 4; ++mi)
#pragma unroll
            for (int r = 0; r < 4; ++r) {
                const int m = n0 + wm + mi * 16 + quad * 4 + r;
#pragma unroll
                for (int nj = 0; nj < 4; ++nj) {
                    const int d = d0 + wn + nj * 16 + lm;
                    UV0[(size_t)m * DD + d] = acc[mi][nj][r] + bias[d];
                }
            }
    } else {
        const float s1 = 1.f - dout[SCR_SC + 1];
        float* EST1 = dout + OFF_EST + (size_t)(b * 2 + 1) * NN * DD;
        unsigned short* E16 = u16p(dout, SCR_E16F) + (size_t)b * NN * 512;
#pragma unroll
        for (int mi = 0; mi < 4; ++mi)
#pragma unroll
            for (int r = 0; r < 4; ++r) {
                const int m = n0 + wm + mi * 16 + quad * 4 + r;
#pragma unroll
                for (int nj = 0; nj < 4; ++nj) {
                    const int d = d0 + wn + nj * 16 + lm;
                    const float v = s1 * (acc[mi][nj][r] + bias[bofs + d]);
                    EST1[(size_t)m * DD + d] = v;
                    E16[(size_t)m * 512 + 256 + d] = (unsigned short)f2bf(v);
                }
            }
    }
}

// =====================================================================
// output projection, MFMA bf16, A from E16, W from b0 tail
// =====================================================================
__global__ __launch_bounds__(256) void k_outproj(const float* __restrict__ bp,
                                                 float* __restrict__ dout)
{
    __shared__ short Al[128 * 40];
    __shared__ short Bl[128 * 40];
    const int z = blockIdx.z;
    const int d0 = blockIdx.x * 128;
    const int b = blockIdx.y >> 4;
    const int n0 = (blockIdx.y & 15) * 128;
    const unsigned short* E16 = u16pc(dout, SCR_E16F) + (size_t)b * NN * 512;
    const unsigned short* W16 = u16pc(dout, SCR_W16P) + (size_t)z * 131072;

    const int t = threadIdx.x, wave = t >> 6, lane = t & 63, quad = lane >> 4, lm = lane & 15;
    const int wm = (wave >> 1) * 64, wn = (wave & 1) * 64;
    const int srow = t >> 1, sch = (t & 1) * 16;

    f32x4 acc[4][4];
#pragma unroll
    for (int i = 0; i < 4; ++i)
#pragma unroll
        for (int j = 0; j < 4; ++j) acc[i][j] = (f32x4){0.f, 0.f, 0.f, 0.f};

    for (int kt = 0; kt < 16; ++kt) {
        const int kk0 = kt * 32;
        const unsigned short* Za = E16 + ((size_t)(n0 + srow)) * 512 + kk0 + sch;
        bf16x8 a0 = *(const bf16x8*)(Za + 0);
        bf16x8 a1 = *(const bf16x8*)(Za + 8);
        const unsigned short* Wa = W16 + (size_t)(d0 + srow) * 512 + kk0 + sch;
        bf16x8 w0 = *(const bf16x8*)(Wa + 0);
        bf16x8 w1 = *(const bf16x8*)(Wa + 8);
        __syncthreads();
        *(bf16x8*)&Al[srow * 40 + sch]     = a0;
        *(bf16x8*)&Al[srow * 40 + sch + 8] = a1;
        *(bf16x8*)&Bl[srow * 40 + sch]     = w0;
        *(bf16x8*)&Bl[srow * 40 + sch + 8] = w1;
        __syncthreads();
        bf16x8 af[4], bff[4];
#pragma unroll
        for (int mi = 0; mi < 4; ++mi) af[mi] = *(const bf16x8*)&Al[(wm + mi * 16 + lm) * 40 + quad * 8];
#pragma unroll
        for (int nj = 0; nj < 4; ++nj) bff[nj] = *(const bf16x8*)&Bl[(wn + nj * 16 + lm) * 40 + quad * 8];
#pragma unroll
        for (int mi = 0; mi < 4; ++mi)
#pragma unroll
            for (int nj = 0; nj < 4; ++nj)
                acc[mi][nj] = __builtin_amdgcn_mfma_f32_16x16x32_bf16(af[mi], bff[nj], acc[mi][nj], 0, 0, 0);
    }
    const int bofs = z ? DD : 0;
    float* O = dout + OFF_OUT + (size_t)(b * 2 + z) * NN * DD;
#pragma unroll
    for (int mi = 0; mi < 4; ++mi)
#pragma unroll
        for (int r = 0; r < 4; ++r) {
            const int m = n0 + wm + mi * 16 + quad * 4 + r;
#pragma unroll
            for (int nj = 0; nj < 4; ++nj) {
                const int d = d0 + wn + nj * 16 + lm;
                O[(size_t)m * DD + d] = acc[mi][nj][r] + bp[bofs + d];
            }
        }
}

// =====================================================================
// transpose V: UV ch0 [b][n][d] fp32 -> VT16 [b][d][n] bf16
// =====================================================================
__global__ void k_vtrans(float* __restrict__ dout) {
    __shared__ float T[64][65];
    const int b = blockIdx.z;
    const int nb = blockIdx.x * 64, db = blockIdx.y * 64;
    const float* V = dout + OFF_UV + (size_t)(b * 2) * NN * DD;
    unsigned short* VT = u16p(dout, SCR_B0) + U_VT16 + (size_t)b * DD * NN;
    const int tr = threadIdx.x >> 4, tc = (threadIdx.x & 15) * 4;
#pragma unroll
    for (int p = 0; p < 4; ++p) {
        float4 v = *(const float4*)&V[(size_t)(nb + tr + p * 16) * DD + db + tc];
        T[tr + p * 16][tc + 0] = v.x; T[tr + p * 16][tc + 1] = v.y;
        T[tr + p * 16][tc + 2] = v.z; T[tr + p * 16][tc + 3] = v.w;
    }
    __syncthreads();
#pragma unroll
    for (int p = 0; p < 4; ++p) {
        const int d = tr + p * 16;
        ushort4 o;
        o.x = (unsigned short)f2bf(T[tc + 0][d]);
        o.y = (unsigned short)f2bf(T[tc + 1][d]);
        o.z = (unsigned short)f2bf(T[tc + 2][d]);
        o.w = (unsigned short)f2bf(T[tc + 3][d]);
        *(ushort4*)&VT[(size_t)(db + d) * NN + nb + tc] = o;
    }
}

// =====================================================================
// causal scores via MFMA QK^T; w = x^{-tau2} unnormalized -> Qij ch0; row sums -> L
// =====================================================================
__global__ __launch_bounds__(256) void k_scores(const float* __restrict__ tmeas,
                                                float* __restrict__ dout) {
    __shared__ short Al[128 * 40];
    __shared__ short Bl[128 * 40];
    const int b = blockIdx.y, x = blockIdx.x;
    int ti = (int)((sqrtf(8.f * x + 1.f) - 1.f) * 0.5f);
    while ((ti + 1) * (ti + 2) / 2 <= x) ++ti;
    while (ti * (ti + 1) / 2 > x) --ti;
    const int tj = x - ti * (ti + 1) / 2;
    const int i0 = ti * 128, j0 = tj * 128;
    const unsigned short* Q16 = u16pc(dout, SCR_B0) + U_Q16 + (size_t)b * NN * DD;
    const unsigned short* K16 = u16pc(dout, SCR_B0) + U_K16 + (size_t)b * NN * DD;
    const int t = threadIdx.x, wave = t >> 6, lane = t & 63, quad = lane >> 4, lm = lane & 15;
    const int wm = (wave >> 1) * 64, wn = (wave & 1) * 64;
    const int srow = t >> 1, sch = (t & 1) * 16;

    f32x4 acc[4][4];
#pragma unroll
    for (int i = 0; i < 4; ++i)
#pragma unroll
        for (int j = 0; j < 4; ++j) acc[i][j] = (f32x4){0.f, 0.f, 0.f, 0.f};

    for (int kt = 0; kt < 8; ++kt) {
        const int kk0 = kt * 32;
        bf16x8 q0 = *(const bf16x8*)(Q16 + (size_t)(i0 + srow) * DD + kk0 + sch);
        bf16x8 q1 = *(const bf16x8*)(Q16 + (size_t)(i0 + srow) * DD + kk0 + sch + 8);
        bf16x8 k0 = *(const bf16x8*)(K16 + (size_t)(j0 + srow) * DD + kk0 + sch);
        bf16x8 k1 = *(const bf16x8*)(K16 + (size_t)(j0 + srow) * DD + kk0 + sch + 8);
        __syncthreads();
        *(bf16x8*)&Al[srow * 40 + sch]     = q0;
        *(bf16x8*)&Al[srow * 40 + sch + 8] = q1;
        *(bf16x8*)&Bl[srow * 40 + sch]     = k0;
        *(bf16x8*)&Bl[srow * 40 + sch + 8] = k1;
        __syncthreads();
        bf16x8 af[4], bff[4];
#pragma unroll
        for (int mi = 0; mi < 4; ++mi) af[mi] = *(const bf16x8*)&Al[(wm + mi * 16 + lm) * 40 + quad * 8];
#pragma unroll
        for (int nj = 0; nj < 4; ++nj) bff[nj] = *(const bf16x8*)&Bl[(wn + nj * 16 + lm) * 40 + quad * 8];
#pragma unroll
        for (int mi = 0; mi < 4; ++mi)
#pragma unroll
            for (int nj = 0; nj < 4; ++nj)
                acc[mi][nj] = __builtin_amdgcn_mfma_f32_16x16x32_bf16(af[mi], bff[nj], acc[mi][nj], 0, 0, 0);
    }

    const float tau2 = dout[SCR_SC + 0], ga = dout[SCR_SC + 2], om = dout[SCR_SC + 3];
    float* Qij = dout + OFF_QIJ + (size_t)b * 2 * NN * NN;
    const float* QN_ = dout + SCR_QN + b * NN;
    const float* KN_ = dout + SCR_KN + b * NN;
    float kn[4], tjv[4]; int jj[4];
#pragma unroll
    for (int nj = 0; nj < 4; ++nj) {
        jj[nj] = j0 + wn + nj * 16 + lm;
        kn[nj] = KN_[jj[nj]];
        tjv[nj] = tmeas[jj[nj]];
    }
#pragma unroll
    for (int mi = 0; mi < 4; ++mi)
#pragma unroll
        for (int r = 0; r < 4; ++r) {
            const int i = i0 + wm + mi * 16 + quad * 4 + r;
            const float qni = QN_[i], tqi = tmeas[i];
            float rs = 0.f;
#pragma unroll
            for (int nj = 0; nj < 4; ++nj) {
                float xx = ga + om * fabsf(tqi - tjv[nj]) + qni + kn[nj] - 2.f * acc[mi][nj][r];
                xx = fmaxf(xx, 1e-30f);
                float w = (tau2 == 1.f) ? (1.f / xx) : __expf(-tau2 * __logf(xx));
                if (jj[nj] > i) w = 0.f;
                Qij[(size_t)i * NN + jj[nj]] = w;
                rs += w;
            }
            rs += __shfl_down(rs, 8, 16); rs += __shfl_down(rs, 4, 16);
            rs += __shfl_down(rs, 2, 16); rs += __shfl_down(rs, 1, 16);
            if (lm == 0) atomicAdd(&dout[SCR_L + b * NN + i], rs);
        }
}

// =====================================================================
// est_inner: A=(w/l) bf16 (normalized write-back), B=V^T bf16
// split-K chunks of 768; bf16 partials -> b1 region (no atomics)
// =====================================================================
__global__ __launch_bounds__(512) void k_estinner(float* __restrict__ dout) {
    __shared__ short Al[128 * 40];   // 10 KB
    __shared__ short Bl[256 * 40];   // 20 KB
    const int b = blockIdx.y;
    int y = blockIdx.x, TI = 0, cb = 0;
    for (;;) { const int nc = nc_of(TI); if (y < nc) break; y -= nc; cb += nc; ++TI; }
    const int i0 = TI * 128;
    const int kbeg = y * 768;
    const int kend = min(kbeg + 768, (TI + 1) * 128);
    const int nst = (kend - kbeg) >> 5;
    const int cidx = cb + y;
    float* Qij = dout + OFF_QIJ + (size_t)b * 2 * NN * NN;
    const unsigned short* VT = u16pc(dout, SCR_B0) + U_VT16 + (size_t)b * DD * NN;

    const int t = threadIdx.x, wave = t >> 6, lane = t & 63, quad = lane >> 4, lm = lane & 15;
    const int wm = (wave >> 2) * 64, wn = (wave & 3) * 64;
    const int arow = t >> 2, acol = (t & 3) * 8;
    const int vrow = t >> 1, vcol = (t & 1) * 16;
    const float linv = 1.f / dout[SCR_L + b * NN + i0 + arow];

    f32x4 acc[4][4];
#pragma unroll
    for (int i = 0; i < 4; ++i)
#pragma unroll
        for (int j = 0; j < 4; ++j) acc[i][j] = (f32x4){0.f, 0.f, 0.f, 0.f};

    for (int kt = 0; kt < nst; ++kt) {
        const int kk0 = kbeg + kt * 32;
        float* Ap = &Qij[(size_t)(i0 + arow) * NN + kk0 + acol];
        float4 w0 = *(const float4*)(Ap + 0);
        float4 w1 = *(const float4*)(Ap + 4);
        w0.x *= linv; w0.y *= linv; w0.z *= linv; w0.w *= linv;
        w1.x *= linv; w1.y *= linv; w1.z *= linv; w1.w *= linv;
        bf16x8 pa;
        pa[0] = f2bf(w0.x); pa[1] = f2bf(w0.y); pa[2] = f2bf(w0.z); pa[3] = f2bf(w0.w);
        pa[4] = f2bf(w1.x); pa[5] = f2bf(w1.y); pa[6] = f2bf(w1.z); pa[7] = f2bf(w1.w);
        bf16x8 v0 = *(const bf16x8*)(VT + (size_t)vrow * NN + kk0 + vcol);
        bf16x8 v1 = *(const bf16x8*)(VT + (size_t)vrow * NN + kk0 + vcol + 8);
        *(float4*)(Ap + 0) = w0;   // normalized write-back
        *(float4*)(Ap + 4) = w1;
        __syncthreads();
        *(bf16x8*)&Al[arow * 40 + acol] = pa;
        *(bf16x8*)&Bl[vrow * 40 + vcol]     = v0;
        *(bf16x8*)&Bl[vrow * 40 + vcol + 8] = v1;
        __syncthreads();
        bf16x8 af[4], bff[4];
#pragma unroll
        for (int mi = 0; mi < 4; ++mi) af[mi] = *(const bf16x8*)&Al[(wm + mi * 16 + lm) * 40 + quad * 8];
#pragma unroll
        for (int nj = 0; nj < 4; ++nj) bff[nj] = *(const bf16x8*)&Bl[(wn + nj * 16 + lm) * 40 + quad * 8];
#pragma unroll
        for (int mi = 0; mi < 4; ++mi)
#pragma unroll
            for (int nj = 0; nj < 4; ++nj)
                acc[mi][nj] = __builtin_amdgcn_mfma_f32_16x16x32_bf16(af[mi], bff[nj], acc[mi][nj], 0, 0, 0);
    }
    unsigned short* P = u16p(dout, SCR_E16F) + U_PART +
                        ((size_t)(b * 30 + cidx)) * 128 * 256;
#pragma unroll
    for (int mi = 0; mi < 4; ++mi)
#pragma unroll
        for (int r = 0; r < 4; ++r) {
            const int ri = wm + mi * 16 + quad * 4 + r;
#pragma unroll
            for (int nj = 0; nj < 4; ++nj) {
                const int d = wn + nj * 16 + lm;
                P[(size_t)ri * 256 + d] = (unsigned short)f2bf(acc[mi][nj][r]);
            }
        }
}

// =====================================================================
// fused blend + structural fills. grid (2048, 1, 18), 256 threads.
// z 0..3: blend b (partials sum -> est ch0 + E16 ch0)
// z 4..7: Qij ch0 strict-upper-128 zeros for b
// z 8: b0 main zero | z 9: b2 zero | z 10: b3 zero
// z 11: VV ch0 ones | z 12: VV ch1 zero | z 13..16: UV ch1 b zero | z 17: LH
// =====================================================================
__global__ void k_blendfills(float* __restrict__ dout) {
    const int z = blockIdx.z;
    if (z < 4) {
        const int b = z;
        if (blockIdx.x >= 512) return;
        const int t = threadIdx.x;
        const int i = blockIdx.x * 4 + (t >> 6);
        const int d4 = (t & 63) * 4;
        const int TI = i >> 7;
        const int nc = nc_of(TI), cb = cb_of(TI);
        const float s = dout[SCR_SC + 1];
        const unsigned short* P = u16pc(dout, SCR_E16F) + U_PART;
        float4 sum = {0.f, 0.f, 0.f, 0.f};
        for (int c = 0; c < nc; ++c) {
            ushort4 pv = *(const ushort4*)&P[((size_t)(b * 30 + cb + c) * 128 + (i & 127)) * 256 + d4];
            sum.x += bf2f(pv.x); sum.y += bf2f(pv.y);
            sum.z += bf2f(pv.z); sum.w += bf2f(pv.w);
        }
        const float4 vr = *(const float4*)&dout[OFF_UV + ((size_t)(b * 2) * NN + i) * DD + d4];
        float4 ev;
        ev.x = (1.f - s) * vr.x + s * sum.x;
        ev.y = (1.f - s) * vr.y + s * sum.y;
        ev.z = (1.f - s) * vr.z + s * sum.z;
        ev.w = (1.f - s) * vr.w + s * sum.w;
        *(float4*)&dout[OFF_EST + ((size_t)(b * 2) * NN + i) * DD + d4] = ev;
        ushort4 o;
        o.x = (unsigned short)f2bf(ev.x); o.y = (unsigned short)f2bf(ev.y);
        o.z = (unsigned short)f2bf(ev.z); o.w = (unsigned short)f2bf(ev.w);
        *(ushort4*)&u16p(dout, SCR_E16F)[((size_t)(b * NN + i)) * 512 + d4] = o;
        return;
    }
    if (z < 8) {
        const int b = z - 4, i = blockIdx.x;
        const int jstart = ((i >> 7) + 1) << 7;
        float* row = dout + OFF_QIJ + (size_t)b * 2 * NN * NN + (size_t)i * NN;
        const float4 zz = {0.f, 0.f, 0.f, 0.f};
        for (int j = jstart + threadIdx.x * 4; j < NN; j += 256 * 4)
            *(float4*)&row[j] = zz;
        return;
    }
    size_t base; long n; float val = 0.f;
    if (z == 8)       { base = SCR_B0; n = 3145728; }
    else if (z == 9)  { base = SCR_Z16F; n = (long)NN * NN; }
    else if (z == 10) { base = SCR_Z16VF; n = (long)NN * NN; }
    else if (z == 11) { base = OFF_VV; n = (long)NN * DD; val = 1.f; }
    else if (z == 12) { base = OFF_VV + (size_t)NN * DD; n = (long)NN * DD; }
    else if (z < 17)  { base = OFF_UV + (size_t)(2 * (z - 13) + 1) * NN * DD; n = (long)NN * DD; }
    else              { base = OFF_LH; n = 512; }
    float* p = dout + base;
    const float4 v = {val, val, val, val};
    for (long i = ((long)blockIdx.x * 256 + threadIdx.x) * 4; i < n;
         i += (long)gridDim.x * 1024)
        *(float4*)&p[i] = v;
}

// zero b1 region (E16 + partials) and b0 tail (norms/SC/W16P) after outproj
__global__ void k_tail(float* __restrict__ dout) {
    const float4 zz = {0.f, 0.f, 0.f, 0.f};
    const long n1 = (long)NN * NN;
    for (long i = ((long)blockIdx.x * 256 + threadIdx.x) * 4; i < n1;
         i += (long)gridDim.x * 1024)
        *(float4*)&dout[SCR_E16F + i] = zz;
    const long n0 = (long)NN * NN - 3145728;  // 1048576 floats
    for (long i = ((long)blockIdx.x * 256 + threadIdx.x) * 4; i < n0;
         i += (long)gridDim.x * 1024)
        *(float4*)&dout[SCR_QN + i] = zz;
}

extern "C" void kernel_launch(void* const* d_in, const int* in_sizes, int n_in,
                              void* d_out, int out_size, void* d_ws, size_t ws_size,
                              hipStream_t stream) {
    const float* Zq = (const float*)d_in[0];
    const float* Zk = (const float*)d_in[1];
    const float* Zv = (const float*)d_in[2];
    const float* tm = (const float*)d_in[3];
    const float* Wq = (const float*)d_in[4];
    const float* bq = (const float*)d_in[5];
    const float* Wk = (const float*)d_in[6];
    const float* bk = (const float*)d_in[7];
    const float* Wv = (const float*)d_in[8];
    const float* bv = (const float*)d_in[9];
    const float* Wp = (const float*)d_in[10];
    const float* bp = (const float*)d_in[11];
    const float* lamOm = (const float*)d_in[13];
    const float* lamGa = (const float*)d_in[14];
    const float* tau = (const float*)d_in[15];
    const float* delta = (const float*)d_in[16];
    const float* lamC = (const float*)d_in[17];
    float* out = (float*)d_out;

    k_cvt<<<dim3(2048, 1, 5), dim3(256), 0, stream>>>(
        Zq, Zk, Zv, Wq, Wk, Wv, Wp, tau, delta, lamOm, lamGa, lamC, out);
    k_qkv<<<dim3(2, 64, 4), dim3(256), 0, stream>>>(bq, bk, bv, out);
    k_vtrans<<<dim3(32, 4, 4), dim3(256), 0, stream>>>(out);
    k_scores<<<dim3(136, 4), dim3(256), 0, stream>>>(tm, out);
    k_estinner<<<dim3(30, 4), dim3(512), 0, stream>>>(out);
    k_blendfills<<<dim3(2048, 1, 18), dim3(256), 0, stream>>>(out);
    k_outproj<<<dim3(2, 64, 2), dim3(256), 0, stream>>>(bp, out);
    k_tail<<<dim3(2048), dim3(256), 0, stream>>>(out);
}